// Round 8
// baseline (444.143 us; speedup 1.0000x reference)
//
#include <hip/hip_runtime.h>
#include <hip/hip_bf16.h>

#define DEV __device__ __forceinline__

constexpr int N_ = 25000;
constexpr int P_ = 400000;

// ---------------- ws layout (units of 4 bytes) ----------------
constexpr int align4(int xx){ return (xx+3)&~3; }
constexpr int OFF_CNT     = 0;                          // N ints (dead after k_scan)
constexpr int OFF_OFFSETS = align4(OFF_CNT + N_);       // N+1 ints
constexpr int OFF_CURSOR  = align4(OFF_OFFSETS + N_ + 1);
constexpr int OFF_SORTED  = align4(OFF_CURSOR + N_);    // P ints
constexpr int OFF_EDGE    = align4(OFF_SORTED + P_);    // P*16 dwords (32 bf16 edge feats, sorted order)
constexpr int OFF_E4      = OFF_EDGE + P_*16;           // P*4  f32
constexpr int OFF_DIR     = OFF_E4 + P_*4;              // P*4  f32
constexpr int OFF_SEM     = align4(OFF_DIR + P_*4);     // N*128 f32
constexpr int OFF_N2      = OFF_SEM + N_*128;           // N*32 f32
constexpr int OFF_DV      = OFF_N2 + N_*32;             // N*4 f32
constexpr int OFF_WB5     = OFF_DV + N_*4;              // wpn1T [64][32]  = 1024 dw
constexpr int OFF_WB6     = OFF_WB5 + 1024;             // wpn2T [64][64]  = 2048 dw
constexpr int OFF_WB7     = OFF_WB6 + 2048;             // wn1T  [64][256] = 8192 dw
constexpr int OFF_WB8     = OFF_WB7 + 8192;             // wn2T  [64][64]  = 2048 dw
constexpr int OFF_WB9     = OFF_WB8 + 2048;             // wv1T  [64][64]  = 2048 dw
constexpr int OFF_HB      = OFF_WB9 + 2048;             // h as bf16: N*32 dw
constexpr int WS_UNITS    = OFF_HB + N_*32;

// transposed bf16 edge weights overlaid on the dead cnt region (13312 dw <= 25000 dw)
constexpr int OFF_WB1 = OFF_CNT;          // [128 n][128 k] bf16 = 8192 dw
constexpr int OFF_WB2 = OFF_WB1 + 8192;   // [64 n][64 k]  bf16 = 2048 dw
constexpr int OFF_WB3 = OFF_WB2 + 2048;   // [32 n][64 k]  bf16 = 1024 dw
constexpr int OFF_WB4 = OFF_WB3 + 1024;   // [128 n][32 k] bf16 = 2048 dw (Wxm^T, n=4c+h)

// PhysNet RBF constants (K=50, r_max=0.5)
constexpr float MU0F  = 0.60653065971263342f;               // exp(-0.5)
constexpr float DMUF  = (1.0f - 0.60653065971263342f) / 49.0f;
constexpr float BETAF = 1.0f / ((0.04f * (1.0f - 0.60653065971263342f)) *
                                (0.04f * (1.0f - 0.60653065971263342f)));
constexpr float EPSF  = 1e-8f;

DEV float u2f(unsigned int u){ union{unsigned int i; float f;} c; c.i=u; return c.f; }
DEV unsigned int f2b16(float f){
  __hip_bfloat16 b = __float2bfloat16(f);
  unsigned short s; __builtin_memcpy(&s, &b, 2);
  return (unsigned int)s;
}
DEV unsigned int pack2(float a, float b){ return f2b16(a) | (f2b16(b) << 16); }
DEV float silu_f(float v){ return v / (1.0f + __expf(-v)); }

using short8 = __attribute__((ext_vector_type(8))) short;   // 8 bf16 (4 VGPRs)
using f32x4  = __attribute__((ext_vector_type(4))) float;
union U4S8 { uint4 u; short8 s; };
DEV short8 ld_frag(const void* p){ U4S8 c; c.u = *(const uint4*)p; return c.s; }
DEV f32x4 mfma16(short8 a, short8 b, f32x4 c){
  return __builtin_amdgcn_mfma_f32_16x16x32_bf16(a, b, c, 0, 0, 0);
}

// ---------------- counting sort by idx_i ----------------
__global__ void k_hist(const int* __restrict__ idx_i, int* __restrict__ cnt){
  int t = blockIdx.x*256 + threadIdx.x;
  if (t < P_) atomicAdd(&cnt[idx_i[t]], 1);
}

__global__ __launch_bounds__(1024) void k_scan(const int* __restrict__ cnt,
                                               int* __restrict__ offsets,
                                               int* __restrict__ cursor){
  __shared__ int swv[16];
  const int t = threadIdx.x;
  const int wv = t >> 6, ln = t & 63;
  constexpr int CH = (N_ + 1023)/1024;   // 25
  int b = t*CH, e = b+CH;
  if (b > N_) b = N_;
  if (e > N_) e = N_;
  int s = 0;
  for (int q=b; q<e; q++) s += cnt[q];
  int incl = s;
  #pragma unroll
  for (int off=1; off<64; off<<=1){
    int vv = __shfl_up(incl, off);
    if (ln >= off) incl += vv;
  }
  if (ln == 63) swv[wv] = incl;
  __syncthreads();
  if (wv == 0 && ln < 16){
    int w = swv[ln];
    #pragma unroll
    for (int off=1; off<16; off<<=1){
      int vv = __shfl_up(w, off);
      if (ln >= off) w += vv;
    }
    swv[ln] = w;
  }
  __syncthreads();
  const int wpre = (wv > 0) ? swv[wv-1] : 0;
  int run = wpre + incl - s;
  for (int q=b; q<e; q++){ offsets[q] = run; cursor[q] = run; run += cnt[q]; }
  if (t == 1023) offsets[N_] = run;
}

__global__ void k_scatter(const int* __restrict__ idx_i, int* __restrict__ cursor,
                          int* __restrict__ sorted){
  int t = blockIdx.x*256 + threadIdx.x;
  if (t < P_){ int pos = atomicAdd(&cursor[idx_i[t]], 1); sorted[pos] = t; }
}

// ---------------- h -> bf16 pre-convert ----------------
__global__ void k_preph(const float* __restrict__ h, unsigned int* __restrict__ hb){
  int t = blockIdx.x*256 + threadIdx.x;
  if (t < N_*32){
    float2 a = *(const float2*)(h + (size_t)t*2);
    hb[t] = pack2(a.x, a.y);
  }
}

// ---------------- weight transpose/convert to bf16 [N][K] ----------------
__global__ void k_prepw(const float* __restrict__ Wein, const float* __restrict__ Weo1,
                        const float* __restrict__ Weo2, const float* __restrict__ Wxm,
                        const float* __restrict__ Wpn1, const float* __restrict__ Wpn2,
                        const float* __restrict__ Wn1,  const float* __restrict__ Wn2,
                        const float* __restrict__ Wv1,
                        unsigned short* __restrict__ wb1, unsigned short* __restrict__ wb2,
                        unsigned short* __restrict__ wb3, unsigned short* __restrict__ wb4,
                        unsigned short* __restrict__ wb5, unsigned short* __restrict__ wb6,
                        unsigned short* __restrict__ wb7, unsigned short* __restrict__ wb8,
                        unsigned short* __restrict__ wb9){
  int t = blockIdx.x*256 + threadIdx.x, st = gridDim.x*256;
  for (int q=t; q<128*128; q+=st){
    int n=q>>7, k=q&127;
    float v = (n<50) ? Wein[k*50+n] : ((n<64) ? 0.f : Weo1[k*64+(n-64)]);
    wb1[q] = (unsigned short)f2b16(v);
  }
  for (int q=t; q<64*64; q+=st){
    int n=q>>6, k=q&63;
    float v = (k<50) ? Weo1[(128+k)*64+n] : ((k==50) ? Weo1[178*64+n] : 0.f);
    wb2[q] = (unsigned short)f2b16(v);
  }
  for (int q=t; q<32*64; q+=st){
    int n=q>>6, k=q&63;
    wb3[q] = (unsigned short)f2b16(Weo2[k*32+n]);
  }
  for (int q=t; q<128*32; q+=st){
    int n=q>>5, k=q&31;
    int cc = n>>2, hh = n&3;
    wb4[q] = (unsigned short)f2b16(Wxm[(k*4+hh)*32 + cc]);
  }
  for (int q=t; q<64*32; q+=st){ int n=q>>5, k=q&31;  wb5[q] = (unsigned short)f2b16(Wpn1[k*64+n]); }
  for (int q=t; q<64*64; q+=st){ int n=q>>6, k=q&63;  wb6[q] = (unsigned short)f2b16(Wpn2[k*64+n]); }
  for (int q=t; q<64*256;q+=st){ int n=q>>8, k=q&255; wb7[q] = (unsigned short)f2b16(Wn1[k*64+n]); }
  for (int q=t; q<64*64; q+=st){ int n=q>>6, k=q&63;  wb8[q] = (unsigned short)f2b16(Wn2[k*64+n]); }
  for (int q=t; q<64*64; q+=st){ int n=q>>6, k=q&63;  wb9[q] = (unsigned short)f2b16(Wv1[k*64+n]); }
}

// ---------------- MFMA edge kernel v3: 2 tiles/wave, register prefetch ----------------
// Per-wave LDS region 9216 B reused across both tiles (A1 264-stride -> A2 -> A3 -> C3).
// Tile1's h-rows prefetched into regs during tile0's epilogue/attention (acc regs dead
// there -> no peak pressure). Geometry+idx for both tiles loaded once; staging gets
// indices via shfl from geometry lanes.
__global__ __launch_bounds__(256, 4) void k_edge3(
    const unsigned short* __restrict__ hb, const float* __restrict__ x,
    const int* __restrict__ idx_i, const int* __restrict__ idx_j,
    const int* __restrict__ sorted,
    const unsigned short* __restrict__ wb1, const unsigned short* __restrict__ wb2,
    const unsigned short* __restrict__ wb3,
    const float* __restrict__ bein, const float* __restrict__ beo1,
    const float* __restrict__ beo2, const float* __restrict__ Watt,
    const float* __restrict__ batt,
    unsigned int* __restrict__ edge_out, float* __restrict__ e4_out,
    float* __restrict__ dir_out)
{
  __shared__ __align__(16) unsigned char sAll[4*9216];   // 36864 B
  __shared__ float sdv[256];
  __shared__ float semd[256];

  const int tid  = threadIdx.x;
  const int wv   = tid >> 6;
  const int lane = tid & 63;
  const int l15  = lane & 15;
  const int quad = lane >> 4;
  const int pbase = blockIdx.x * 256;
  unsigned char* sW = sAll + wv*9216;

  // ---- geometry: each lane covers one row (tile = lane>>5, row = lane&31) ----
  const int t_g = lane >> 5, r_g = lane & 31;
  const int p2 = pbase + t_g*128 + 32*wv + r_g;
  const bool pv = p2 < P_;
  const int pp = sorted[pv ? p2 : 0];
  const int ii = idx_i[pp], jj = idx_j[pp];
  {
    float xi0=x[ii*3], xi1=x[ii*3+1], xi2=x[ii*3+2];
    float xj0=x[jj*3], xj1=x[jj*3+1], xj2=x[jj*3+2];
    float rx=xj0-xi0, ry=xj1-xi1, rz=xj2-xi2;
    float d = sqrtf(rx*rx+ry*ry+rz*rz+EPSF);
    float iv = 1.0f/(d+EPSF);
    int slot = t_g*128 + 32*wv + r_g;
    sdv[slot] = d;
    semd[slot] = __expf(-d);
    if (pv) *(float4*)(dir_out + (size_t)p2*4) = make_float4(rx*iv, ry*iv, rz*iv, d);
  }

  const bool t1v = (pbase + 128 + 32*wv + 32) <= P_;   // wave-uniform

  // ---- prefetch tile0 h rows into regs (idx via shfl from geometry lanes) ----
  uint4 pre[8];
  {
    int src = (lane >> 1);                       // tile0 geometry lane for row rr
    int hi = __shfl(ii, src), hj = __shfl(jj, src);
    int hidx = (lane & 1) ? hj : hi;
    const uint4* hp = (const uint4*)(hb + (size_t)hidx*64);
    #pragma unroll
    for (int q=0;q<8;q++) pre[q] = hp[q];
  }

  #pragma unroll
  for (int t=0; t<2; t++){
    if (t==1 && !t1v) break;
    const int tbase = pbase + t*128 + 32*wv;     // first pair of this wave's tile
    const int sbase = t*128 + 32*wv;             // sdv/semd base

    // ---- staged regs -> LDS A1 (rows local 0..31, 264 B stride) ----
    {
      int rr = lane >> 1;
      unsigned char* dst = sW + rr*264 + (lane&1)*128;
      #pragma unroll
      for (int q=0;q<8;q++) *(uint4*)(dst + q*16) = pre[q];
    }

    // ---- GEMM-1: [32 x 128] @ WB1 [128 x 128] ----
    f32x4 acc[2][8];
    #pragma unroll
    for (int mf=0; mf<2; mf++)
      #pragma unroll
      for (int nf=0; nf<8; nf++){
        float bias;
        if (nf < 4){ int nn = 16*nf + l15; bias = (nn < 50) ? bein[nn] : 0.f; }
        else       { bias = beo1[16*(nf-4) + l15]; }
        acc[mf][nf] = (f32x4){bias, bias, bias, bias};
      }
    #pragma unroll
    for (int s=0; s<4; s++){
      int koff = s*32 + quad*8;
      short8 a0 = ld_frag(sW + l15*264      + koff*2);
      short8 a1 = ld_frag(sW + (16+l15)*264 + koff*2);
      #pragma unroll
      for (int nf=0; nf<8; nf++){
        short8 b = ld_frag((const unsigned char*)wb1 + (16*nf + l15)*256 + koff*2);
        acc[0][nf] = mfma16(a0, b, acc[0][nf]);
        acc[1][nf] = mfma16(a1, b, acc[1][nf]);
      }
    }

    // ---- epilogue 1: RBF -> A2 bf16 [lrow][72 ushort] at sW+0 (A1 dead) ----
    #pragma unroll
    for (int mf=0; mf<2; mf++)
      #pragma unroll
      for (int nf=0; nf<4; nf++){
        int n = 16*nf + l15;
        float mu = MU0F + (float)n*DMUF;
        #pragma unroll
        for (int reg=0; reg<4; reg++){
          int lrow = 16*mf + quad*4 + reg;
          float tt = semd[sbase + lrow] - mu;
          float fv = acc[mf][nf][reg] * __expf(-BETAF*tt*tt);
          unsigned short ob;
          if (n < 50)       ob = (unsigned short)f2b16(fv);
          else if (n == 50) ob = (unsigned short)f2b16(sdv[sbase + lrow]);
          else              ob = 0;
          ((unsigned short*)sW)[lrow*72 + n] = ob;
        }
      }

    // ---- GEMM-2: += A2 [32 x 64] @ WB2 [64 x 64] ----
    #pragma unroll
    for (int s=0; s<2; s++){
      int koff = s*32 + quad*8;
      short8 a0 = ld_frag(sW + l15*144      + koff*2);
      short8 a1 = ld_frag(sW + (16+l15)*144 + koff*2);
      #pragma unroll
      for (int nf=0; nf<4; nf++){
        short8 b = ld_frag((const unsigned char*)wb2 + (16*nf + l15)*128 + koff*2);
        acc[0][4+nf] = mfma16(a0, b, acc[0][4+nf]);
        acc[1][4+nf] = mfma16(a1, b, acc[1][4+nf]);
      }
    }

    // ---- epilogue 2: silu -> A3 bf16 at sW+4608 ----
    unsigned char* A3 = sW + 4608;
    #pragma unroll
    for (int mf=0; mf<2; mf++)
      #pragma unroll
      for (int nf=0; nf<4; nf++){
        int n = 16*nf + l15;
        #pragma unroll
        for (int reg=0; reg<4; reg++){
          int lrow = 16*mf + quad*4 + reg;
          ((unsigned short*)A3)[lrow*72 + n] = (unsigned short)f2b16(silu_f(acc[mf][4+nf][reg]));
        }
      }

    // ---- GEMM-3: [32 x 64] @ WB3 [64 x 32] ----
    f32x4 acc3[2][2];
    #pragma unroll
    for (int mf=0; mf<2; mf++)
      #pragma unroll
      for (int nf=0; nf<2; nf++){
        float bias = beo2[16*nf + l15];
        acc3[mf][nf] = (f32x4){bias, bias, bias, bias};
      }
    #pragma unroll
    for (int s=0; s<2; s++){
      int koff = s*32 + quad*8;
      short8 a0 = ld_frag(A3 + l15*144      + koff*2);
      short8 a1 = ld_frag(A3 + (16+l15)*144 + koff*2);
      #pragma unroll
      for (int nf=0; nf<2; nf++){
        short8 b = ld_frag((const unsigned char*)wb3 + (16*nf + l15)*128 + koff*2);
        acc3[0][nf] = mfma16(a0, b, acc3[0][nf]);
        acc3[1][nf] = mfma16(a1, b, acc3[1][nf]);
      }
    }

    // ---- epilogue 3: C3 f32 [lrow][36 f32] at sW+0 (A2 dead) ----
    #pragma unroll
    for (int mf=0; mf<2; mf++)
      #pragma unroll
      for (int nf=0; nf<2; nf++){
        int n = 16*nf + l15;
        #pragma unroll
        for (int reg=0; reg<4; reg++){
          int lrow = 16*mf + quad*4 + reg;
          ((float*)sW)[lrow*36 + n] = acc3[mf][nf][reg];
        }
      }

    // ---- prefetch tile1 h rows (overlaps attention below; acc regs dead here) ----
    if (t==0 && t1v){
      int src = 32 + (lane >> 1);                // tile1 geometry lane for row rr
      int hi = __shfl(ii, src), hj = __shfl(jj, src);
      int hidx = (lane & 1) ? hj : hi;
      const uint4* hp = (const uint4*)(hb + (size_t)hidx*64);
      #pragma unroll
      for (int q=0;q<8;q++) pre[q] = hp[q];
    }

    // ---- attention + stores (2 lanes per row) ----
    {
      int rr = lane >> 1;
      int p = tbase + rr;
      int cb = (lane & 1) * 16;
      const float* er = (const float*)(sW + rr*144);
      float l0, l1, l2, l3;
      if ((lane & 1) == 0){ l0 = batt[0]; l1 = batt[1]; l2 = batt[2]; l3 = batt[3]; }
      else                { l0 = l1 = l2 = l3 = 0.f; }
      float ecache[16];
      #pragma unroll
      for (int c=0;c<16;c++){
        float ev = er[cb + c];
        ecache[c] = ev;
        const float4 wr = *(const float4*)(Watt + (cb + c)*4);
        l0 += ev*wr.x; l1 += ev*wr.y; l2 += ev*wr.z; l3 += ev*wr.w;
      }
      l0 += __shfl_xor(l0,1); l1 += __shfl_xor(l1,1);
      l2 += __shfl_xor(l2,1); l3 += __shfl_xor(l3,1);
      if ((lane & 1) == 0){
        float e0 = __expf(l0 > 0.f ? l0 : 2.f*(__expf(l0*0.5f)-1.f));
        float e1 = __expf(l1 > 0.f ? l1 : 2.f*(__expf(l1*0.5f)-1.f));
        float e2 = __expf(l2 > 0.f ? l2 : 2.f*(__expf(l2*0.5f)-1.f));
        float e3 = __expf(l3 > 0.f ? l3 : 2.f*(__expf(l3*0.5f)-1.f));
        *(float4*)(e4_out + (size_t)p*4) = make_float4(e0, e1, e2, e3);
      }
      uint4 o1 = make_uint4(pack2(ecache[0],ecache[1]),  pack2(ecache[2],ecache[3]),
                            pack2(ecache[4],ecache[5]),  pack2(ecache[6],ecache[7]));
      uint4 o2 = make_uint4(pack2(ecache[8],ecache[9]),  pack2(ecache[10],ecache[11]),
                            pack2(ecache[12],ecache[13]),pack2(ecache[14],ecache[15]));
      unsigned int* ep = edge_out + (size_t)p*16 + (lane&1)*8;
      *(uint4*)(ep)     = o1;
      *(uint4*)(ep + 4) = o2;
    }
  }
}

// ---------------- aggregation kernel: 4 waves/block, 1 node/wave ----------------
// Finer granularity (grid x4) de-phase-locks waves and shortens per-wave serial
// chains; first-chunk staging issued before the denominator pass (independent).
__global__ __launch_bounds__(256, 4) void k_agg(
    const int* __restrict__ offsets,
    const unsigned int* __restrict__ edgeb,
    const float* __restrict__ e4,
    const float* __restrict__ dir4,
    const unsigned short* __restrict__ wb4,
    const float* __restrict__ Wvm,
    float* __restrict__ wsSem, float* __restrict__ wsN2, float* __restrict__ wsDv)
{
  __shared__ __align__(16) unsigned char sAllB[4*10240];
  const int wv   = threadIdx.x >> 6;
  const int lane = threadIdx.x & 63;
  unsigned char* sA = sAllB + wv*10240;
  unsigned char* gC = sA + 2048;

  const int c    = lane & 31;
  const int l15  = lane & 15;
  const int quad = lane >> 4;
  const bool low = (lane < 32);

  short8 b4[8];
  #pragma unroll
  for (int nf=0; nf<8; nf++)
    b4[nf] = ld_frag((const unsigned char*)wb4 + (16*nf + l15)*64 + quad*16);
  const float wvm_c = Wvm[c];

  const int i = blockIdx.x*4 + wv;
  if (i >= N_) return;
  const int n0 = offsets[i], n1 = offsets[i+1];
  const int cnt = n1 - n0;

  // issue first-chunk staging before the denominator pass (independent streams)
  {
    const int nc0 = min(32, cnt);
    if (lane*32 < nc0*64){
      const uint4* src = (const uint4*)(edgeb + (size_t)n0*16 + lane*8);
      *(uint4*)(sA + lane*32)      = src[0];
      *(uint4*)(sA + lane*32 + 16) = src[1];
    }
  }

  float d0=0.f,d1=0.f,d2=0.f,d3=0.f;
  for (int s = n0 + lane; s < n1; s += 64){
    const float4 ev = *(const float4*)(e4 + (size_t)s*4);
    d0+=ev.x; d1+=ev.y; d2+=ev.z; d3+=ev.w;
  }
  #pragma unroll
  for (int off=32; off>=1; off>>=1){
    d0 += __shfl_xor(d0,off); d1 += __shfl_xor(d1,off);
    d2 += __shfl_xor(d2,off); d3 += __shfl_xor(d3,off);
  }
  const float i0 = (cnt>0)?1.f/d0:0.f, i1 = (cnt>0)?1.f/d1:0.f;
  const float i2 = (cnt>0)?1.f/d2:0.f, i3 = (cnt>0)?1.f/d3:0.f;

  float sem4[4] = {0.f,0.f,0.f,0.f};
  float cx=0.f,cy=0.f,cz=0.f, gx=0.f,gy=0.f,gz=0.f;

  bool staged = true;                    // first chunk already staged
  for (int base = n0; base < n1; base += 32){
    const int nc = min(32, n1 - base);
    if (!staged){
      if (lane*32 < nc*64){
        const uint4* src = (const uint4*)(edgeb + (size_t)base*16 + lane*8);
        *(uint4*)(sA + lane*32)      = src[0];
        *(uint4*)(sA + lane*32 + 16) = src[1];
      }
    }
    staged = false;
    short8 a0 = ld_frag(sA + l15*64 + quad*16);
    f32x4 accg[2][8];
    #pragma unroll
    for (int nf=0; nf<8; nf++){
      f32x4 z = (f32x4){0.f,0.f,0.f,0.f};
      accg[0][nf] = mfma16(a0, b4[nf], z);
    }
    if (nc > 16){
      short8 a1 = ld_frag(sA + (16+l15)*64 + quad*16);
      #pragma unroll
      for (int nf=0; nf<8; nf++){
        f32x4 z = (f32x4){0.f,0.f,0.f,0.f};
        accg[1][nf] = mfma16(a1, b4[nf], z);
      }
    }
    #pragma unroll
    for (int nf=0; nf<8; nf++){
      int n = 16*nf + l15;
      #pragma unroll
      for (int reg=0; reg<4; reg++){
        int row = quad*4 + reg;
        ((unsigned short*)gC)[row*128 + n] = (unsigned short)f2b16(accg[0][nf][reg]);
      }
    }
    if (nc > 16){
      #pragma unroll
      for (int nf=0; nf<8; nf++){
        int n = 16*nf + l15;
        #pragma unroll
        for (int reg=0; reg<4; reg++){
          int row = 16 + quad*4 + reg;
          ((unsigned short*)gC)[row*128 + n] = (unsigned short)f2b16(accg[1][nf][reg]);
        }
      }
    }
    for (int t0 = 0; t0 < nc; t0 += 2){
      const int rloc = t0 + (lane >> 5);
      const bool act = rloc < nc;
      const int s = base + (act ? rloc : 0);
      const float4 ev = *(const float4*)(e4 + (size_t)s*4);
      const float4 dv = *(const float4*)(dir4 + (size_t)s*4);
      const float aw0 = ev.x*i0, aw1 = ev.y*i1, aw2 = ev.z*i2, aw3 = ev.w*i3;
      uint2 gv = *(const uint2*)(gC + rloc*256 + c*8);
      float g0=u2f(gv.x<<16), g1=u2f(gv.x&0xffff0000u);
      float g2=u2f(gv.y<<16), g3=u2f(gv.y&0xffff0000u);
      float tp = aw0*g0 + aw1*g1 + aw2*g2 + aw3*g3;
      float tt = fminf(fmaxf(tp, -15.f), 15.f);
      float ex = __expf(2.f*tt);
      float th = (ex-1.f)/(ex+1.f);
      unsigned int ew = *(const unsigned int*)(sA + rloc*64 + (c>>1)*4);
      float ec = (c & 1) ? u2f(ew & 0xffff0000u) : u2f(ew << 16);
      if (act){
        sem4[0] += ec*aw0; sem4[1] += ec*aw1;
        sem4[2] += ec*aw2; sem4[3] += ec*aw3;
        cx += th*dv.x; cy += th*dv.y; cz += th*dv.z;
        float tw = th*wvm_c;
        gx += tw*dv.x; gy += tw*dv.y; gz += tw*dv.z;
      }
    }
  }

  #pragma unroll
  for (int j=0;j<4;j++) sem4[j] += __shfl_xor(sem4[j], 32);
  cx += __shfl_xor(cx,32); cy += __shfl_xor(cy,32); cz += __shfl_xor(cz,32);
  #pragma unroll
  for (int off=32; off>=1; off>>=1){
    gx += __shfl_xor(gx,off); gy += __shfl_xor(gy,off); gz += __shfl_xor(gz,off);
  }
  const float invc = 1.f/(float)(cnt > 1 ? cnt : 1);
  if (low){
    float mx = cx*invc, my = cy*invc, mz = cz*invc;
    wsN2[(size_t)i*32 + c] = mx*mx + my*my + mz*mz;
    *(float4*)(wsSem + (size_t)i*128 + 4*c) = make_float4(sem4[0], sem4[1], sem4[2], sem4[3]);
  }
  if (lane == 0)
    *(float4*)(wsDv + (size_t)i*4) = make_float4(gx*invc, gy*invc, gz*invc, 0.f);
}

// ---------------- node MLP kernel: batched MFMA GEMM, 128 nodes/block ----------------
__global__ __launch_bounds__(256) void k_mlp(
    const float* __restrict__ h, const float* __restrict__ x, const float* __restrict__ v,
    const float* __restrict__ wsSem, const float* __restrict__ wsN2,
    const float* __restrict__ wsDv,
    const unsigned short* __restrict__ wb5, const unsigned short* __restrict__ wb6,
    const unsigned short* __restrict__ wb7, const unsigned short* __restrict__ wb8,
    const unsigned short* __restrict__ wb9,
    const float* __restrict__ bpn1, const float* __restrict__ bpn2,
    const float* __restrict__ bn1,  const float* __restrict__ bn2,
    const float* __restrict__ bv1,  const float* __restrict__ Wv2,
    float* __restrict__ out)
{
  __shared__ __align__(16) unsigned char sH[128*136];
  __shared__ __align__(16) unsigned char sSem[128*264];
  __shared__ __align__(16) unsigned char sSp[128*136];
  __shared__ __align__(16) unsigned char sN2[128*72];
  __shared__ __align__(16) unsigned char sTmp[128*136];

  const int tid  = threadIdx.x;
  const int wv   = tid >> 6;
  const int lane = tid & 63;
  const int l15  = lane & 15;
  const int quad = lane >> 4;
  const int i0   = blockIdx.x*128;
  const int r0   = 32*wv;

  for (int idx = tid; idx < 128*16; idx += 256){
    int row = idx >> 4, c4 = idx & 15;
    int node = min(i0 + row, N_-1);
    float4 a = *(const float4*)(h + (size_t)node*64 + c4*4);
    *(uint2*)(sH + row*136 + c4*8) = make_uint2(pack2(a.x,a.y), pack2(a.z,a.w));
  }
  for (int idx = tid; idx < 128*32; idx += 256){
    int row = idx >> 5, c4 = idx & 31;
    int node = min(i0 + row, N_-1);
    float4 a = *(const float4*)(wsSem + (size_t)node*128 + c4*4);
    *(uint2*)(sSem + row*264 + c4*8) = make_uint2(pack2(a.x,a.y), pack2(a.z,a.w));
  }
  for (int idx = tid; idx < 128*8; idx += 256){
    int row = idx >> 3, c4 = idx & 7;
    int node = min(i0 + row, N_-1);
    float4 a = *(const float4*)(wsN2 + (size_t)node*32 + c4*4);
    *(uint2*)(sN2 + row*72 + c4*8) = make_uint2(pack2(a.x,a.y), pack2(a.z,a.w));
  }
  __syncthreads();

  // S1
  {
    f32x4 acc[2][4];
    #pragma unroll
    for (int mf=0; mf<2; mf++)
      #pragma unroll
      for (int nf=0; nf<4; nf++){ float b = bpn1[16*nf+l15]; acc[mf][nf] = (f32x4){b,b,b,b}; }
    short8 a0 = ld_frag(sN2 + (r0+l15)*72 + quad*16);
    short8 a1 = ld_frag(sN2 + (r0+16+l15)*72 + quad*16);
    #pragma unroll
    for (int nf=0; nf<4; nf++){
      short8 b = ld_frag((const unsigned char*)wb5 + (16*nf+l15)*64 + quad*16);
      acc[0][nf] = mfma16(a0, b, acc[0][nf]);
      acc[1][nf] = mfma16(a1, b, acc[1][nf]);
    }
    #pragma unroll
    for (int mf=0; mf<2; mf++)
      #pragma unroll
      for (int nf=0; nf<4; nf++){
        int n = 16*nf + l15;
        #pragma unroll
        for (int reg=0; reg<4; reg++){
          int row = r0 + 16*mf + quad*4 + reg;
          ((unsigned short*)(sTmp + row*136))[n] = (unsigned short)f2b16(silu_f(acc[mf][nf][reg]));
        }
      }
  }
  // S2
  {
    f32x4 acc[2][4];
    #pragma unroll
    for (int mf=0; mf<2; mf++)
      #pragma unroll
      for (int nf=0; nf<4; nf++){ float b = bpn2[16*nf+l15]; acc[mf][nf] = (f32x4){b,b,b,b}; }
    #pragma unroll
    for (int s=0; s<2; s++){
      int koff = s*32 + quad*8;
      short8 a0 = ld_frag(sTmp + (r0+l15)*136 + koff*2);
      short8 a1 = ld_frag(sTmp + (r0+16+l15)*136 + koff*2);
      #pragma unroll
      for (int nf=0; nf<4; nf++){
        short8 b = ld_frag((const unsigned char*)wb6 + (16*nf+l15)*128 + koff*2);
        acc[0][nf] = mfma16(a0, b, acc[0][nf]);
        acc[1][nf] = mfma16(a1, b, acc[1][nf]);
      }
    }
    #pragma unroll
    for (int mf=0; mf<2; mf++)
      #pragma unroll
      for (int nf=0; nf<4; nf++){
        int n = 16*nf + l15;
        #pragma unroll
        for (int reg=0; reg<4; reg++){
          int row = r0 + 16*mf + quad*4 + reg;
          ((unsigned short*)(sSp + row*136))[n] = (unsigned short)f2b16(silu_f(acc[mf][nf][reg]));
        }
      }
  }
  // N1 (K=256)
  {
    f32x4 acc[2][4];
    #pragma unroll
    for (int mf=0; mf<2; mf++)
      #pragma unroll
      for (int nf=0; nf<4; nf++){ float b = bn1[16*nf+l15]; acc[mf][nf] = (f32x4){b,b,b,b}; }
    #pragma unroll
    for (int s=0; s<8; s++){
      int koff = s*32 + quad*8;
      const unsigned char *pa0, *pa1;
      if (koff < 64){ pa0 = sH + (r0+l15)*136 + koff*2;          pa1 = sH + (r0+16+l15)*136 + koff*2; }
      else if (koff < 192){ pa0 = sSem + (r0+l15)*264 + (koff-64)*2;  pa1 = sSem + (r0+16+l15)*264 + (koff-64)*2; }
      else { pa0 = sSp + (r0+l15)*136 + (koff-192)*2;            pa1 = sSp + (r0+16+l15)*136 + (koff-192)*2; }
      short8 a0 = ld_frag(pa0);
      short8 a1 = ld_frag(pa1);
      #pragma unroll
      for (int nf=0; nf<4; nf++){
        short8 b = ld_frag((const unsigned char*)wb7 + (16*nf+l15)*512 + koff*2);
        acc[0][nf] = mfma16(a0, b, acc[0][nf]);
        acc[1][nf] = mfma16(a1, b, acc[1][nf]);
      }
    }
    #pragma unroll
    for (int mf=0; mf<2; mf++)
      #pragma unroll
      for (int nf=0; nf<4; nf++){
        int n = 16*nf + l15;
        #pragma unroll
        for (int reg=0; reg<4; reg++){
          int row = r0 + 16*mf + quad*4 + reg;
          ((unsigned short*)(sTmp + row*136))[n] = (unsigned short)f2b16(silu_f(acc[mf][nf][reg]));
        }
      }
  }
  // N2 + residual
  {
    f32x4 acc[2][4];
    #pragma unroll
    for (int mf=0; mf<2; mf++)
      #pragma unroll
      for (int nf=0; nf<4; nf++){ float b = bn2[16*nf+l15]; acc[mf][nf] = (f32x4){b,b,b,b}; }
    #pragma unroll
    for (int s=0; s<2; s++){
      int koff = s*32 + quad*8;
      short8 a0 = ld_frag(sTmp + (r0+l15)*136 + koff*2);
      short8 a1 = ld_frag(sTmp + (r0+16+l15)*136 + koff*2);
      #pragma unroll
      for (int nf=0; nf<4; nf++){
        short8 b = ld_frag((const unsigned char*)wb8 + (16*nf+l15)*128 + koff*2);
        acc[0][nf] = mfma16(a0, b, acc[0][nf]);
        acc[1][nf] = mfma16(a1, b, acc[1][nf]);
      }
    }
    #pragma unroll
    for (int mf=0; mf<2; mf++)
      #pragma unroll
      for (int nf=0; nf<4; nf++){
        int n = 16*nf + l15;
        #pragma unroll
        for (int reg=0; reg<4; reg++){
          int row = r0 + 16*mf + quad*4 + reg;
          int node = i0 + row;
          float hv = (node < N_) ? h[(size_t)node*64 + n] : 0.f;
          float hnew = hv + silu_f(acc[mf][nf][reg]);
          if (node < N_) out[(size_t)node*64 + n] = hnew;
          ((unsigned short*)(sH + row*136))[n] = (unsigned short)f2b16(hnew);
        }
      }
  }
  // V1 + gate + v/x
  {
    f32x4 acc[2][4];
    #pragma unroll
    for (int mf=0; mf<2; mf++)
      #pragma unroll
      for (int nf=0; nf<4; nf++){ float b = bv1[16*nf+l15]; acc[mf][nf] = (f32x4){b,b,b,b}; }
    #pragma unroll
    for (int s=0; s<2; s++){
      int koff = s*32 + quad*8;
      short8 a0 = ld_frag(sH + (r0+l15)*136 + koff*2);
      short8 a1 = ld_frag(sH + (r0+16+l15)*136 + koff*2);
      #pragma unroll
      for (int nf=0; nf<4; nf++){
        short8 b = ld_frag((const unsigned char*)wb9 + (16*nf+l15)*128 + koff*2);
        acc[0][nf] = mfma16(a0, b, acc[0][nf]);
        acc[1][nf] = mfma16(a1, b, acc[1][nf]);
      }
    }
    float part[2][4] = {{0.f,0.f,0.f,0.f},{0.f,0.f,0.f,0.f}};
    #pragma unroll
    for (int mf=0; mf<2; mf++)
      #pragma unroll
      for (int nf=0; nf<4; nf++){
        float w2 = Wv2[16*nf + l15];
        #pragma unroll
        for (int reg=0; reg<4; reg++)
          part[mf][reg] += silu_f(acc[mf][nf][reg]) * w2;
      }
    #pragma unroll
    for (int mf=0; mf<2; mf++)
      #pragma unroll
      for (int reg=0; reg<4; reg++){
        #pragma unroll
        for (int off=1; off<16; off<<=1)
          part[mf][reg] += __shfl_xor(part[mf][reg], off);
      }
    if (l15 == 0){
      #pragma unroll
      for (int mf=0; mf<2; mf++)
        #pragma unroll
        for (int reg=0; reg<4; reg++){
          int row = r0 + 16*mf + quad*4 + reg;
          int node = i0 + row;
          if (node < N_){
            float gate = 2.f/(1.f + __expf(-part[mf][reg]));
            float4 dvv = *(const float4*)(wsDv + (size_t)node*4);
            float dvs[3] = {dvv.x, dvv.y, dvv.z};
            #pragma unroll
            for (int ax=0; ax<3; ax++){
              float vn = gate * v[(size_t)node*3 + ax] + dvs[ax];
              out[(size_t)N_*64 + (size_t)node*3 + ax]                 = x[(size_t)node*3 + ax] + vn;
              out[(size_t)N_*64 + (size_t)N_*3 + (size_t)node*3 + ax]  = vn;
            }
          }
        }
    }
  }
}

// ---------------- launch ----------------
extern "C" void kernel_launch(void* const* d_in, const int* in_sizes, int n_in,
                              void* d_out, int out_size, void* d_ws, size_t ws_size,
                              hipStream_t stream)
{
  const float* h = (const float*)d_in[0];
  const float* x = (const float*)d_in[1];
  const float* v = (const float*)d_in[2];
  const int* idx_i = (const int*)d_in[3];
  const int* idx_j = (const int*)d_in[4];
  const float* Wein = (const float*)d_in[5];  const float* bein = (const float*)d_in[6];
  const float* Weo1 = (const float*)d_in[7];  const float* beo1 = (const float*)d_in[8];
  const float* Weo2 = (const float*)d_in[9];  const float* beo2 = (const float*)d_in[10];
  const float* Watt = (const float*)d_in[11]; const float* batt = (const float*)d_in[12];
  const float* Wxm  = (const float*)d_in[13]; const float* Wvm  = (const float*)d_in[14];
  const float* Wpn1 = (const float*)d_in[15]; const float* bpn1 = (const float*)d_in[16];
  const float* Wpn2 = (const float*)d_in[17]; const float* bpn2 = (const float*)d_in[18];
  const float* Wn1  = (const float*)d_in[19]; const float* bn1  = (const float*)d_in[20];
  const float* Wn2  = (const float*)d_in[21]; const float* bn2  = (const float*)d_in[22];
  const float* Wv1  = (const float*)d_in[23]; const float* bv1  = (const float*)d_in[24];
  const float* Wv2  = (const float*)d_in[25];

  float* wsf        = (float*)d_ws;
  int*   cnt        = (int*)(wsf + OFF_CNT);
  int*   offsets    = (int*)(wsf + OFF_OFFSETS);
  int*   cursor     = (int*)(wsf + OFF_CURSOR);
  int*   sorted     = (int*)(wsf + OFF_SORTED);
  unsigned int* edgeb = (unsigned int*)(wsf + OFF_EDGE);
  float* e4o        = wsf + OFF_E4;
  float* diro       = wsf + OFF_DIR;
  float* wsSem      = wsf + OFF_SEM;
  float* wsN2       = wsf + OFF_N2;
  float* wsDv       = wsf + OFF_DV;
  unsigned short* wb1 = (unsigned short*)(wsf + OFF_WB1);
  unsigned short* wb2 = (unsigned short*)(wsf + OFF_WB2);
  unsigned short* wb3 = (unsigned short*)(wsf + OFF_WB3);
  unsigned short* wb4 = (unsigned short*)(wsf + OFF_WB4);
  unsigned short* wb5 = (unsigned short*)(wsf + OFF_WB5);
  unsigned short* wb6 = (unsigned short*)(wsf + OFF_WB6);
  unsigned short* wb7 = (unsigned short*)(wsf + OFF_WB7);
  unsigned short* wb8 = (unsigned short*)(wsf + OFF_WB8);
  unsigned short* wb9 = (unsigned short*)(wsf + OFF_WB9);
  unsigned int*   hb  = (unsigned int*)(wsf + OFF_HB);

  hipMemsetAsync(cnt, 0, N_*sizeof(int), stream);
  k_hist<<<(P_+255)/256, 256, 0, stream>>>(idx_i, cnt);
  k_scan<<<1, 1024, 0, stream>>>(cnt, offsets, cursor);
  k_prepw<<<32, 256, 0, stream>>>(Wein, Weo1, Weo2, Wxm, Wpn1, Wpn2, Wn1, Wn2, Wv1,
                                  wb1, wb2, wb3, wb4, wb5, wb6, wb7, wb8, wb9);
  k_preph<<<(N_*32+255)/256, 256, 0, stream>>>(h, hb);
  k_scatter<<<(P_+255)/256, 256, 0, stream>>>(idx_i, cursor, sorted);
  k_edge3<<<(P_+255)/256, 256, 0, stream>>>((const unsigned short*)hb, x, idx_i, idx_j, sorted,
                                            wb1, wb2, wb3,
                                            bein, beo1, beo2, Watt, batt,
                                            edgeb, e4o, diro);
  k_agg<<<(N_+3)/4, 256, 0, stream>>>(offsets, edgeb, e4o, diro, wb4, Wvm,
                                      wsSem, wsN2, wsDv);
  k_mlp<<<(N_+127)/128, 256, 0, stream>>>(h, x, v, wsSem, wsN2, wsDv,
                                          wb5, wb6, wb7, wb8, wb9,
                                          bpn1, bpn2, bn1, bn2, bv1, Wv2,
                                          (float*)d_out);
}

// Round 9
// 386.256 us; speedup vs baseline: 1.1499x; 1.1499x over previous
//
#include <hip/hip_runtime.h>
#include <hip/hip_bf16.h>

#define DEV __device__ __forceinline__

constexpr int N_ = 25000;
constexpr int P_ = 400000;

// ---------------- ws layout (units of 4 bytes) ----------------
constexpr int align4(int xx){ return (xx+3)&~3; }
constexpr int OFF_CNT     = 0;                          // N ints (dead after k_scan)
constexpr int OFF_OFFSETS = align4(OFF_CNT + N_);       // N+1 ints
constexpr int OFF_CURSOR  = align4(OFF_OFFSETS + N_ + 1);
constexpr int OFF_SORTED  = align4(OFF_CURSOR + N_);    // P ints
constexpr int OFF_EDGE    = align4(OFF_SORTED + P_);    // P*16 dwords (32 bf16 edge feats, sorted order)
constexpr int OFF_E4      = OFF_EDGE + P_*16;           // P*4  f32
constexpr int OFF_DIR     = OFF_E4 + P_*4;              // P*4  f32
constexpr int OFF_SEM     = align4(OFF_DIR + P_*4);     // N*128 f32
constexpr int OFF_N2      = OFF_SEM + N_*128;           // N*32 f32
constexpr int OFF_DV      = OFF_N2 + N_*32;             // N*4 f32
constexpr int OFF_WB5     = OFF_DV + N_*4;              // wpn1T [64][32]  = 1024 dw
constexpr int OFF_WB6     = OFF_WB5 + 1024;             // wpn2T [64][64]  = 2048 dw
constexpr int OFF_WB7     = OFF_WB6 + 2048;             // wn1T  [64][256] = 8192 dw
constexpr int OFF_WB8     = OFF_WB7 + 8192;             // wn2T  [64][64]  = 2048 dw
constexpr int OFF_WB9     = OFF_WB8 + 2048;             // wv1T  [64][64]  = 2048 dw
constexpr int OFF_HB      = OFF_WB9 + 2048;             // h as bf16: N*32 dw
constexpr int WS_UNITS    = OFF_HB + N_*32;

// transposed bf16 edge weights overlaid on the dead cnt region (13312 dw <= 25000 dw)
constexpr int OFF_WB1 = OFF_CNT;          // [128 n][128 k] bf16 = 8192 dw
constexpr int OFF_WB2 = OFF_WB1 + 8192;   // [64 n][64 k]  bf16 = 2048 dw
constexpr int OFF_WB3 = OFF_WB2 + 2048;   // [32 n][64 k]  bf16 = 1024 dw
constexpr int OFF_WB4 = OFF_WB3 + 1024;   // [128 n][32 k] bf16 = 2048 dw (Wxm^T, n=4c+h)

// PhysNet RBF constants (K=50, r_max=0.5)
constexpr float MU0F  = 0.60653065971263342f;               // exp(-0.5)
constexpr float DMUF  = (1.0f - 0.60653065971263342f) / 49.0f;
constexpr float BETAF = 1.0f / ((0.04f * (1.0f - 0.60653065971263342f)) *
                                (0.04f * (1.0f - 0.60653065971263342f)));
constexpr float EPSF  = 1e-8f;

DEV float u2f(unsigned int u){ union{unsigned int i; float f;} c; c.i=u; return c.f; }
DEV unsigned int f2b16(float f){
  __hip_bfloat16 b = __float2bfloat16(f);
  unsigned short s; __builtin_memcpy(&s, &b, 2);
  return (unsigned int)s;
}
DEV unsigned int pack2(float a, float b){ return f2b16(a) | (f2b16(b) << 16); }
DEV float silu_f(float v){ return v / (1.0f + __expf(-v)); }

using short8 = __attribute__((ext_vector_type(8))) short;   // 8 bf16 (4 VGPRs)
using f32x4  = __attribute__((ext_vector_type(4))) float;
union U4S8 { uint4 u; short8 s; };
DEV short8 ld_frag(const void* p){ U4S8 c; c.u = *(const uint4*)p; return c.s; }
DEV f32x4 mfma16(short8 a, short8 b, f32x4 c){
  return __builtin_amdgcn_mfma_f32_16x16x32_bf16(a, b, c, 0, 0, 0);
}

// ---------------- counting sort by idx_i ----------------
__global__ void k_hist(const int* __restrict__ idx_i, int* __restrict__ cnt){
  int t = blockIdx.x*256 + threadIdx.x;
  if (t < P_) atomicAdd(&cnt[idx_i[t]], 1);
}

__global__ __launch_bounds__(1024) void k_scan(const int* __restrict__ cnt,
                                               int* __restrict__ offsets,
                                               int* __restrict__ cursor){
  __shared__ int swv[16];
  const int t = threadIdx.x;
  const int wv = t >> 6, ln = t & 63;
  constexpr int CH = (N_ + 1023)/1024;   // 25
  int b = t*CH, e = b+CH;
  if (b > N_) b = N_;
  if (e > N_) e = N_;
  int s = 0;
  for (int q=b; q<e; q++) s += cnt[q];
  int incl = s;
  #pragma unroll
  for (int off=1; off<64; off<<=1){
    int vv = __shfl_up(incl, off);
    if (ln >= off) incl += vv;
  }
  if (ln == 63) swv[wv] = incl;
  __syncthreads();
  if (wv == 0 && ln < 16){
    int w = swv[ln];
    #pragma unroll
    for (int off=1; off<16; off<<=1){
      int vv = __shfl_up(w, off);
      if (ln >= off) w += vv;
    }
    swv[ln] = w;
  }
  __syncthreads();
  const int wpre = (wv > 0) ? swv[wv-1] : 0;
  int run = wpre + incl - s;
  for (int q=b; q<e; q++){ offsets[q] = run; cursor[q] = run; run += cnt[q]; }
  if (t == 1023) offsets[N_] = run;
}

__global__ void k_scatter(const int* __restrict__ idx_i, int* __restrict__ cursor,
                          int* __restrict__ sorted){
  int t = blockIdx.x*256 + threadIdx.x;
  if (t < P_){ int pos = atomicAdd(&cursor[idx_i[t]], 1); sorted[pos] = t; }
}

// ---------------- h -> bf16 pre-convert ----------------
__global__ void k_preph(const float* __restrict__ h, unsigned int* __restrict__ hb){
  int t = blockIdx.x*256 + threadIdx.x;
  if (t < N_*32){
    float2 a = *(const float2*)(h + (size_t)t*2);
    hb[t] = pack2(a.x, a.y);
  }
}

// ---------------- weight transpose/convert to bf16 [N][K] ----------------
__global__ void k_prepw(const float* __restrict__ Wein, const float* __restrict__ Weo1,
                        const float* __restrict__ Weo2, const float* __restrict__ Wxm,
                        const float* __restrict__ Wpn1, const float* __restrict__ Wpn2,
                        const float* __restrict__ Wn1,  const float* __restrict__ Wn2,
                        const float* __restrict__ Wv1,
                        unsigned short* __restrict__ wb1, unsigned short* __restrict__ wb2,
                        unsigned short* __restrict__ wb3, unsigned short* __restrict__ wb4,
                        unsigned short* __restrict__ wb5, unsigned short* __restrict__ wb6,
                        unsigned short* __restrict__ wb7, unsigned short* __restrict__ wb8,
                        unsigned short* __restrict__ wb9){
  int t = blockIdx.x*256 + threadIdx.x, st = gridDim.x*256;
  for (int q=t; q<128*128; q+=st){
    int n=q>>7, k=q&127;
    float v = (n<50) ? Wein[k*50+n] : ((n<64) ? 0.f : Weo1[k*64+(n-64)]);
    wb1[q] = (unsigned short)f2b16(v);
  }
  for (int q=t; q<64*64; q+=st){
    int n=q>>6, k=q&63;
    float v = (k<50) ? Weo1[(128+k)*64+n] : ((k==50) ? Weo1[178*64+n] : 0.f);
    wb2[q] = (unsigned short)f2b16(v);
  }
  for (int q=t; q<32*64; q+=st){
    int n=q>>6, k=q&63;
    wb3[q] = (unsigned short)f2b16(Weo2[k*32+n]);
  }
  for (int q=t; q<128*32; q+=st){
    int n=q>>5, k=q&31;
    int cc = n>>2, hh = n&3;
    wb4[q] = (unsigned short)f2b16(Wxm[(k*4+hh)*32 + cc]);
  }
  for (int q=t; q<64*32; q+=st){ int n=q>>5, k=q&31;  wb5[q] = (unsigned short)f2b16(Wpn1[k*64+n]); }
  for (int q=t; q<64*64; q+=st){ int n=q>>6, k=q&63;  wb6[q] = (unsigned short)f2b16(Wpn2[k*64+n]); }
  for (int q=t; q<64*256;q+=st){ int n=q>>8, k=q&255; wb7[q] = (unsigned short)f2b16(Wn1[k*64+n]); }
  for (int q=t; q<64*64; q+=st){ int n=q>>6, k=q&63;  wb8[q] = (unsigned short)f2b16(Wn2[k*64+n]); }
  for (int q=t; q<64*64; q+=st){ int n=q>>6, k=q&63;  wb9[q] = (unsigned short)f2b16(Wv1[k*64+n]); }
}

// ---------------- MFMA edge kernel: sorted order, low-AGPR split ----------------
// Per-wave region 9216 B: A1 [32][264 B]; A2 bf16 [32][144] at +0 (A1 data kept in
// register A-fragments); A3 bf16 [32][144] at +4608; C3 f32 [32][144] at +0.
// GEMM-1 split into two 64-wide N halves reusing 32 AGPRs (peak regs ~96-110 ->
// 4 waves/SIMD; was 144 -> 3). DS in-order per wave -> overlays safe.
__global__ __launch_bounds__(256, 4) void k_edge2(
    const unsigned short* __restrict__ hb, const float* __restrict__ x,
    const int* __restrict__ idx_i, const int* __restrict__ idx_j,
    const int* __restrict__ sorted,
    const unsigned short* __restrict__ wb1, const unsigned short* __restrict__ wb2,
    const unsigned short* __restrict__ wb3,
    const float* __restrict__ bein, const float* __restrict__ beo1,
    const float* __restrict__ beo2, const float* __restrict__ Watt,
    const float* __restrict__ batt,
    unsigned int* __restrict__ edge_out, float* __restrict__ e4_out,
    float* __restrict__ dir_out)
{
  __shared__ __align__(16) unsigned char sAll[4*9216];   // 36864 B
  __shared__ float sdv[128];
  __shared__ float semd[128];

  const int tid  = threadIdx.x;
  const int wv   = tid >> 6;
  const int lane = tid & 63;
  const int l15  = lane & 15;
  const int quad = lane >> 4;
  const int pbase = blockIdx.x * 128;
  unsigned char* sW = sAll + wv*9216;

  // ---- geometry (lanes 0..31; wave-local rows) ----
  if (lane < 32){
    int row = 32*wv + lane;
    int p2 = pbase + row;
    int pp = sorted[p2];
    int ii = idx_i[pp], jj = idx_j[pp];
    float xi0=x[ii*3], xi1=x[ii*3+1], xi2=x[ii*3+2];
    float xj0=x[jj*3], xj1=x[jj*3+1], xj2=x[jj*3+2];
    float rx=xj0-xi0, ry=xj1-xi1, rz=xj2-xi2;
    float d = sqrtf(rx*rx+ry*ry+rz*rz+EPSF);
    float iv = 1.0f/(d+EPSF);
    sdv[row] = d;
    semd[row] = __expf(-d);
    *(float4*)(dir_out + (size_t)p2*4) = make_float4(rx*iv, ry*iv, rz*iv, d);
  }

  // ---- stage A1 = hcat bf16 (2 threads/row; direct 128 B copies) ----
  {
    int rr = lane >> 1;
    int pp1 = sorted[pbase + 32*wv + rr];
    int hidx = (lane & 1) ? idx_j[pp1] : idx_i[pp1];
    const uint4* hp = (const uint4*)(hb + (size_t)hidx*64);
    unsigned char* dst = sW + rr*264 + (lane&1)*128;
    #pragma unroll
    for (int q=0;q<8;q++) *(uint4*)(dst + q*16) = hp[q];
  }

  // ---- load all A-fragments into registers (A1 then reusable as A2) ----
  short8 af0[4], af1[4];
  #pragma unroll
  for (int s=0; s<4; s++){
    int koff = s*32 + quad*8;
    af0[s] = ld_frag(sW + l15*264      + koff*2);
    af1[s] = ld_frag(sW + (16+l15)*264 + koff*2);
  }

  // ---- GEMM-1a: [32 x 128] @ WB1[:, 0..63] (Wein -> filtered pre-RBF) ----
  f32x4 acc[2][4];
  #pragma unroll
  for (int mf=0; mf<2; mf++)
    #pragma unroll
    for (int nf=0; nf<4; nf++){
      int nn = 16*nf + l15;
      float bias = (nn < 50) ? bein[nn] : 0.f;
      acc[mf][nf] = (f32x4){bias, bias, bias, bias};
    }
  #pragma unroll
  for (int s=0; s<4; s++){
    int koff = s*32 + quad*8;
    #pragma unroll
    for (int nf=0; nf<4; nf++){
      short8 b = ld_frag((const unsigned char*)wb1 + (16*nf + l15)*256 + koff*2);
      acc[0][nf] = mfma16(af0[s], b, acc[0][nf]);
      acc[1][nf] = mfma16(af1[s], b, acc[1][nf]);
    }
  }

  // ---- epilogue 1: RBF -> A2 bf16 [lrow][72 ushort] at sW+0 (frees acc) ----
  #pragma unroll
  for (int mf=0; mf<2; mf++)
    #pragma unroll
    for (int nf=0; nf<4; nf++){
      int n = 16*nf + l15;
      float mu = MU0F + (float)n*DMUF;
      #pragma unroll
      for (int reg=0; reg<4; reg++){
        int lrow = 16*mf + quad*4 + reg;
        int grow = 32*wv + lrow;
        float t = semd[grow] - mu;
        float fv = acc[mf][nf][reg] * __expf(-BETAF*t*t);
        unsigned short ob;
        if (n < 50)       ob = (unsigned short)f2b16(fv);
        else if (n == 50) ob = (unsigned short)f2b16(sdv[grow]);
        else              ob = 0;
        ((unsigned short*)sW)[lrow*72 + n] = ob;
      }
    }

  // ---- GEMM-1b: [32 x 128] @ WB1[:, 64..127] (Weo1-top) into reused acc ----
  #pragma unroll
  for (int mf=0; mf<2; mf++)
    #pragma unroll
    for (int nf=0; nf<4; nf++){
      float bias = beo1[16*nf + l15];
      acc[mf][nf] = (f32x4){bias, bias, bias, bias};
    }
  #pragma unroll
  for (int s=0; s<4; s++){
    int koff = s*32 + quad*8;
    #pragma unroll
    for (int nf=0; nf<4; nf++){
      short8 b = ld_frag((const unsigned char*)wb1 + (64 + 16*nf + l15)*256 + koff*2);
      acc[0][nf] = mfma16(af0[s], b, acc[0][nf]);
      acc[1][nf] = mfma16(af1[s], b, acc[1][nf]);
    }
  }

  // ---- GEMM-2: += A2 [32 x 64] @ WB2 [64 x 64] ----
  #pragma unroll
  for (int s=0; s<2; s++){
    int koff = s*32 + quad*8;
    short8 a0 = ld_frag(sW + l15*144      + koff*2);
    short8 a1 = ld_frag(sW + (16+l15)*144 + koff*2);
    #pragma unroll
    for (int nf=0; nf<4; nf++){
      short8 b = ld_frag((const unsigned char*)wb2 + (16*nf + l15)*128 + koff*2);
      acc[0][nf] = mfma16(a0, b, acc[0][nf]);
      acc[1][nf] = mfma16(a1, b, acc[1][nf]);
    }
  }

  // ---- epilogue 2: silu -> A3 bf16 at sW+4608 (frees acc) ----
  unsigned char* A3 = sW + 4608;
  #pragma unroll
  for (int mf=0; mf<2; mf++)
    #pragma unroll
    for (int nf=0; nf<4; nf++){
      int n = 16*nf + l15;
      #pragma unroll
      for (int reg=0; reg<4; reg++){
        int lrow = 16*mf + quad*4 + reg;
        ((unsigned short*)A3)[lrow*72 + n] = (unsigned short)f2b16(silu_f(acc[mf][nf][reg]));
      }
    }

  // ---- GEMM-3: [32 x 64] @ WB3 [64 x 32] ----
  f32x4 acc3[2][2];
  #pragma unroll
  for (int mf=0; mf<2; mf++)
    #pragma unroll
    for (int nf=0; nf<2; nf++){
      float bias = beo2[16*nf + l15];
      acc3[mf][nf] = (f32x4){bias, bias, bias, bias};
    }
  #pragma unroll
  for (int s=0; s<2; s++){
    int koff = s*32 + quad*8;
    short8 a0 = ld_frag(A3 + l15*144      + koff*2);
    short8 a1 = ld_frag(A3 + (16+l15)*144 + koff*2);
    #pragma unroll
    for (int nf=0; nf<2; nf++){
      short8 b = ld_frag((const unsigned char*)wb3 + (16*nf + l15)*128 + koff*2);
      acc3[0][nf] = mfma16(a0, b, acc3[0][nf]);
      acc3[1][nf] = mfma16(a1, b, acc3[1][nf]);
    }
  }

  // ---- epilogue 3: C3 f32 [lrow][36 f32] at sW+0 (A2 dead) ----
  #pragma unroll
  for (int mf=0; mf<2; mf++)
    #pragma unroll
    for (int nf=0; nf<2; nf++){
      int n = 16*nf + l15;
      #pragma unroll
      for (int reg=0; reg<4; reg++){
        int lrow = 16*mf + quad*4 + reg;
        ((float*)sW)[lrow*36 + n] = acc3[mf][nf][reg];
      }
    }

  // ---- attention + stores (2 lanes per row) ----
  {
    int rr = lane >> 1;
    int p = pbase + 32*wv + rr;
    int cb = (lane & 1) * 16;
    const float* er = (const float*)(sW + rr*144);
    float l0, l1, l2, l3;
    if ((lane & 1) == 0){ l0 = batt[0]; l1 = batt[1]; l2 = batt[2]; l3 = batt[3]; }
    else                { l0 = l1 = l2 = l3 = 0.f; }
    float ecache[16];
    #pragma unroll
    for (int c=0;c<16;c++){
      float ev = er[cb + c];
      ecache[c] = ev;
      const float4 wr = *(const float4*)(Watt + (cb + c)*4);
      l0 += ev*wr.x; l1 += ev*wr.y; l2 += ev*wr.z; l3 += ev*wr.w;
    }
    l0 += __shfl_xor(l0,1); l1 += __shfl_xor(l1,1);
    l2 += __shfl_xor(l2,1); l3 += __shfl_xor(l3,1);
    if ((lane & 1) == 0){
      float e0 = __expf(l0 > 0.f ? l0 : 2.f*(__expf(l0*0.5f)-1.f));
      float e1 = __expf(l1 > 0.f ? l1 : 2.f*(__expf(l1*0.5f)-1.f));
      float e2 = __expf(l2 > 0.f ? l2 : 2.f*(__expf(l2*0.5f)-1.f));
      float e3 = __expf(l3 > 0.f ? l3 : 2.f*(__expf(l3*0.5f)-1.f));
      *(float4*)(e4_out + (size_t)p*4) = make_float4(e0, e1, e2, e3);
    }
    uint4 o1 = make_uint4(pack2(ecache[0],ecache[1]),  pack2(ecache[2],ecache[3]),
                          pack2(ecache[4],ecache[5]),  pack2(ecache[6],ecache[7]));
    uint4 o2 = make_uint4(pack2(ecache[8],ecache[9]),  pack2(ecache[10],ecache[11]),
                          pack2(ecache[12],ecache[13]),pack2(ecache[14],ecache[15]));
    unsigned int* ep = edge_out + (size_t)p*16 + (lane&1)*8;
    *(uint4*)(ep)     = o1;
    *(uint4*)(ep + 4) = o2;
  }
}

// ---------------- aggregation kernel: 4 waves/block, 1 node/wave, low-AGPR ----------
// accg half 0 computed+written back before half 1 is computed (peak 32 AGPR).
__global__ __launch_bounds__(256, 4) void k_agg(
    const int* __restrict__ offsets,
    const unsigned int* __restrict__ edgeb,
    const float* __restrict__ e4,
    const float* __restrict__ dir4,
    const unsigned short* __restrict__ wb4,
    const float* __restrict__ Wvm,
    float* __restrict__ wsSem, float* __restrict__ wsN2, float* __restrict__ wsDv)
{
  __shared__ __align__(16) unsigned char sAllB[4*10240];
  const int wv   = threadIdx.x >> 6;
  const int lane = threadIdx.x & 63;
  unsigned char* sA = sAllB + wv*10240;
  unsigned char* gC = sA + 2048;

  const int c    = lane & 31;
  const int l15  = lane & 15;
  const int quad = lane >> 4;
  const bool low = (lane < 32);

  short8 b4[8];
  #pragma unroll
  for (int nf=0; nf<8; nf++)
    b4[nf] = ld_frag((const unsigned char*)wb4 + (16*nf + l15)*64 + quad*16);
  const float wvm_c = Wvm[c];

  const int i = blockIdx.x*4 + wv;
  if (i >= N_) return;
  const int n0 = offsets[i], n1 = offsets[i+1];
  const int cnt = n1 - n0;

  // issue first-chunk staging before the denominator pass (independent streams)
  {
    const int nc0 = min(32, cnt);
    if (lane*32 < nc0*64){
      const uint4* src = (const uint4*)(edgeb + (size_t)n0*16 + lane*8);
      *(uint4*)(sA + lane*32)      = src[0];
      *(uint4*)(sA + lane*32 + 16) = src[1];
    }
  }

  float d0=0.f,d1=0.f,d2=0.f,d3=0.f;
  for (int s = n0 + lane; s < n1; s += 64){
    const float4 ev = *(const float4*)(e4 + (size_t)s*4);
    d0+=ev.x; d1+=ev.y; d2+=ev.z; d3+=ev.w;
  }
  #pragma unroll
  for (int off=32; off>=1; off>>=1){
    d0 += __shfl_xor(d0,off); d1 += __shfl_xor(d1,off);
    d2 += __shfl_xor(d2,off); d3 += __shfl_xor(d3,off);
  }
  const float i0 = (cnt>0)?1.f/d0:0.f, i1 = (cnt>0)?1.f/d1:0.f;
  const float i2 = (cnt>0)?1.f/d2:0.f, i3 = (cnt>0)?1.f/d3:0.f;

  float sem4[4] = {0.f,0.f,0.f,0.f};
  float cx=0.f,cy=0.f,cz=0.f, gx=0.f,gy=0.f,gz=0.f;

  bool staged = true;                    // first chunk already staged
  for (int base = n0; base < n1; base += 32){
    const int nc = min(32, n1 - base);
    if (!staged){
      if (lane*32 < nc*64){
        const uint4* src = (const uint4*)(edgeb + (size_t)base*16 + lane*8);
        *(uint4*)(sA + lane*32)      = src[0];
        *(uint4*)(sA + lane*32 + 16) = src[1];
      }
    }
    staged = false;
    // half 0: rows 0..15 — compute then write back (frees accg before half 1)
    {
      short8 a0 = ld_frag(sA + l15*64 + quad*16);
      f32x4 accg[8];
      #pragma unroll
      for (int nf=0; nf<8; nf++){
        f32x4 z = (f32x4){0.f,0.f,0.f,0.f};
        accg[nf] = mfma16(a0, b4[nf], z);
      }
      #pragma unroll
      for (int nf=0; nf<8; nf++){
        int n = 16*nf + l15;
        #pragma unroll
        for (int reg=0; reg<4; reg++){
          int row = quad*4 + reg;
          ((unsigned short*)gC)[row*128 + n] = (unsigned short)f2b16(accg[nf][reg]);
        }
      }
    }
    // half 1: rows 16..31 (reuses the same AGPRs)
    if (nc > 16){
      short8 a1 = ld_frag(sA + (16+l15)*64 + quad*16);
      f32x4 accg[8];
      #pragma unroll
      for (int nf=0; nf<8; nf++){
        f32x4 z = (f32x4){0.f,0.f,0.f,0.f};
        accg[nf] = mfma16(a1, b4[nf], z);
      }
      #pragma unroll
      for (int nf=0; nf<8; nf++){
        int n = 16*nf + l15;
        #pragma unroll
        for (int reg=0; reg<4; reg++){
          int row = 16 + quad*4 + reg;
          ((unsigned short*)gC)[row*128 + n] = (unsigned short)f2b16(accg[nf][reg]);
        }
      }
    }
    for (int t0 = 0; t0 < nc; t0 += 2){
      const int rloc = t0 + (lane >> 5);
      const bool act = rloc < nc;
      const int s = base + (act ? rloc : 0);
      const float4 ev = *(const float4*)(e4 + (size_t)s*4);
      const float4 dv = *(const float4*)(dir4 + (size_t)s*4);
      const float aw0 = ev.x*i0, aw1 = ev.y*i1, aw2 = ev.z*i2, aw3 = ev.w*i3;
      uint2 gv = *(const uint2*)(gC + rloc*256 + c*8);
      float g0=u2f(gv.x<<16), g1=u2f(gv.x&0xffff0000u);
      float g2=u2f(gv.y<<16), g3=u2f(gv.y&0xffff0000u);
      float tp = aw0*g0 + aw1*g1 + aw2*g2 + aw3*g3;
      float tt = fminf(fmaxf(tp, -15.f), 15.f);
      float ex = __expf(2.f*tt);
      float th = (ex-1.f)/(ex+1.f);
      unsigned int ew = *(const unsigned int*)(sA + rloc*64 + (c>>1)*4);
      float ec = (c & 1) ? u2f(ew & 0xffff0000u) : u2f(ew << 16);
      if (act){
        sem4[0] += ec*aw0; sem4[1] += ec*aw1;
        sem4[2] += ec*aw2; sem4[3] += ec*aw3;
        cx += th*dv.x; cy += th*dv.y; cz += th*dv.z;
        float tw = th*wvm_c;
        gx += tw*dv.x; gy += tw*dv.y; gz += tw*dv.z;
      }
    }
  }

  #pragma unroll
  for (int j=0;j<4;j++) sem4[j] += __shfl_xor(sem4[j], 32);
  cx += __shfl_xor(cx,32); cy += __shfl_xor(cy,32); cz += __shfl_xor(cz,32);
  #pragma unroll
  for (int off=32; off>=1; off>>=1){
    gx += __shfl_xor(gx,off); gy += __shfl_xor(gy,off); gz += __shfl_xor(gz,off);
  }
  const float invc = 1.f/(float)(cnt > 1 ? cnt : 1);
  if (low){
    float mx = cx*invc, my = cy*invc, mz = cz*invc;
    wsN2[(size_t)i*32 + c] = mx*mx + my*my + mz*mz;
    *(float4*)(wsSem + (size_t)i*128 + 4*c) = make_float4(sem4[0], sem4[1], sem4[2], sem4[3]);
  }
  if (lane == 0)
    *(float4*)(wsDv + (size_t)i*4) = make_float4(gx*invc, gy*invc, gz*invc, 0.f);
}

// ---------------- node MLP kernel: batched MFMA GEMM, 128 nodes/block ----------------
__global__ __launch_bounds__(256) void k_mlp(
    const float* __restrict__ h, const float* __restrict__ x, const float* __restrict__ v,
    const float* __restrict__ wsSem, const float* __restrict__ wsN2,
    const float* __restrict__ wsDv,
    const unsigned short* __restrict__ wb5, const unsigned short* __restrict__ wb6,
    const unsigned short* __restrict__ wb7, const unsigned short* __restrict__ wb8,
    const unsigned short* __restrict__ wb9,
    const float* __restrict__ bpn1, const float* __restrict__ bpn2,
    const float* __restrict__ bn1,  const float* __restrict__ bn2,
    const float* __restrict__ bv1,  const float* __restrict__ Wv2,
    float* __restrict__ out)
{
  __shared__ __align__(16) unsigned char sH[128*136];
  __shared__ __align__(16) unsigned char sSem[128*264];
  __shared__ __align__(16) unsigned char sSp[128*136];
  __shared__ __align__(16) unsigned char sN2[128*72];
  __shared__ __align__(16) unsigned char sTmp[128*136];

  const int tid  = threadIdx.x;
  const int wv   = tid >> 6;
  const int lane = tid & 63;
  const int l15  = lane & 15;
  const int quad = lane >> 4;
  const int i0   = blockIdx.x*128;
  const int r0   = 32*wv;

  for (int idx = tid; idx < 128*16; idx += 256){
    int row = idx >> 4, c4 = idx & 15;
    int node = min(i0 + row, N_-1);
    float4 a = *(const float4*)(h + (size_t)node*64 + c4*4);
    *(uint2*)(sH + row*136 + c4*8) = make_uint2(pack2(a.x,a.y), pack2(a.z,a.w));
  }
  for (int idx = tid; idx < 128*32; idx += 256){
    int row = idx >> 5, c4 = idx & 31;
    int node = min(i0 + row, N_-1);
    float4 a = *(const float4*)(wsSem + (size_t)node*128 + c4*4);
    *(uint2*)(sSem + row*264 + c4*8) = make_uint2(pack2(a.x,a.y), pack2(a.z,a.w));
  }
  for (int idx = tid; idx < 128*8; idx += 256){
    int row = idx >> 3, c4 = idx & 7;
    int node = min(i0 + row, N_-1);
    float4 a = *(const float4*)(wsN2 + (size_t)node*32 + c4*4);
    *(uint2*)(sN2 + row*72 + c4*8) = make_uint2(pack2(a.x,a.y), pack2(a.z,a.w));
  }
  __syncthreads();

  // S1
  {
    f32x4 acc[2][4];
    #pragma unroll
    for (int mf=0; mf<2; mf++)
      #pragma unroll
      for (int nf=0; nf<4; nf++){ float b = bpn1[16*nf+l15]; acc[mf][nf] = (f32x4){b,b,b,b}; }
    short8 a0 = ld_frag(sN2 + (r0+l15)*72 + quad*16);
    short8 a1 = ld_frag(sN2 + (r0+16+l15)*72 + quad*16);
    #pragma unroll
    for (int nf=0; nf<4; nf++){
      short8 b = ld_frag((const unsigned char*)wb5 + (16*nf+l15)*64 + quad*16);
      acc[0][nf] = mfma16(a0, b, acc[0][nf]);
      acc[1][nf] = mfma16(a1, b, acc[1][nf]);
    }
    #pragma unroll
    for (int mf=0; mf<2; mf++)
      #pragma unroll
      for (int nf=0; nf<4; nf++){
        int n = 16*nf + l15;
        #pragma unroll
        for (int reg=0; reg<4; reg++){
          int row = r0 + 16*mf + quad*4 + reg;
          ((unsigned short*)(sTmp + row*136))[n] = (unsigned short)f2b16(silu_f(acc[mf][nf][reg]));
        }
      }
  }
  // S2
  {
    f32x4 acc[2][4];
    #pragma unroll
    for (int mf=0; mf<2; mf++)
      #pragma unroll
      for (int nf=0; nf<4; nf++){ float b = bpn2[16*nf+l15]; acc[mf][nf] = (f32x4){b,b,b,b}; }
    #pragma unroll
    for (int s=0; s<2; s++){
      int koff = s*32 + quad*8;
      short8 a0 = ld_frag(sTmp + (r0+l15)*136 + koff*2);
      short8 a1 = ld_frag(sTmp + (r0+16+l15)*136 + koff*2);
      #pragma unroll
      for (int nf=0; nf<4; nf++){
        short8 b = ld_frag((const unsigned char*)wb6 + (16*nf+l15)*128 + koff*2);
        acc[0][nf] = mfma16(a0, b, acc[0][nf]);
        acc[1][nf] = mfma16(a1, b, acc[1][nf]);
      }
    }
    #pragma unroll
    for (int mf=0; mf<2; mf++)
      #pragma unroll
      for (int nf=0; nf<4; nf++){
        int n = 16*nf + l15;
        #pragma unroll
        for (int reg=0; reg<4; reg++){
          int row = r0 + 16*mf + quad*4 + reg;
          ((unsigned short*)(sSp + row*136))[n] = (unsigned short)f2b16(silu_f(acc[mf][nf][reg]));
        }
      }
  }
  // N1 (K=256)
  {
    f32x4 acc[2][4];
    #pragma unroll
    for (int mf=0; mf<2; mf++)
      #pragma unroll
      for (int nf=0; nf<4; nf++){ float b = bn1[16*nf+l15]; acc[mf][nf] = (f32x4){b,b,b,b}; }
    #pragma unroll
    for (int s=0; s<8; s++){
      int koff = s*32 + quad*8;
      const unsigned char *pa0, *pa1;
      if (koff < 64){ pa0 = sH + (r0+l15)*136 + koff*2;          pa1 = sH + (r0+16+l15)*136 + koff*2; }
      else if (koff < 192){ pa0 = sSem + (r0+l15)*264 + (koff-64)*2;  pa1 = sSem + (r0+16+l15)*264 + (koff-64)*2; }
      else { pa0 = sSp + (r0+l15)*136 + (koff-192)*2;            pa1 = sSp + (r0+16+l15)*136 + (koff-192)*2; }
      short8 a0 = ld_frag(pa0);
      short8 a1 = ld_frag(pa1);
      #pragma unroll
      for (int nf=0; nf<4; nf++){
        short8 b = ld_frag((const unsigned char*)wb7 + (16*nf+l15)*512 + koff*2);
        acc[0][nf] = mfma16(a0, b, acc[0][nf]);
        acc[1][nf] = mfma16(a1, b, acc[1][nf]);
      }
    }
    #pragma unroll
    for (int mf=0; mf<2; mf++)
      #pragma unroll
      for (int nf=0; nf<4; nf++){
        int n = 16*nf + l15;
        #pragma unroll
        for (int reg=0; reg<4; reg++){
          int row = r0 + 16*mf + quad*4 + reg;
          ((unsigned short*)(sTmp + row*136))[n] = (unsigned short)f2b16(silu_f(acc[mf][nf][reg]));
        }
      }
  }
  // N2 + residual
  {
    f32x4 acc[2][4];
    #pragma unroll
    for (int mf=0; mf<2; mf++)
      #pragma unroll
      for (int nf=0; nf<4; nf++){ float b = bn2[16*nf+l15]; acc[mf][nf] = (f32x4){b,b,b,b}; }
    #pragma unroll
    for (int s=0; s<2; s++){
      int koff = s*32 + quad*8;
      short8 a0 = ld_frag(sTmp + (r0+l15)*136 + koff*2);
      short8 a1 = ld_frag(sTmp + (r0+16+l15)*136 + koff*2);
      #pragma unroll
      for (int nf=0; nf<4; nf++){
        short8 b = ld_frag((const unsigned char*)wb8 + (16*nf+l15)*128 + koff*2);
        acc[0][nf] = mfma16(a0, b, acc[0][nf]);
        acc[1][nf] = mfma16(a1, b, acc[1][nf]);
      }
    }
    #pragma unroll
    for (int mf=0; mf<2; mf++)
      #pragma unroll
      for (int nf=0; nf<4; nf++){
        int n = 16*nf + l15;
        #pragma unroll
        for (int reg=0; reg<4; reg++){
          int row = r0 + 16*mf + quad*4 + reg;
          int node = i0 + row;
          float hv = (node < N_) ? h[(size_t)node*64 + n] : 0.f;
          float hnew = hv + silu_f(acc[mf][nf][reg]);
          if (node < N_) out[(size_t)node*64 + n] = hnew;
          ((unsigned short*)(sH + row*136))[n] = (unsigned short)f2b16(hnew);
        }
      }
  }
  // V1 + gate + v/x
  {
    f32x4 acc[2][4];
    #pragma unroll
    for (int mf=0; mf<2; mf++)
      #pragma unroll
      for (int nf=0; nf<4; nf++){ float b = bv1[16*nf+l15]; acc[mf][nf] = (f32x4){b,b,b,b}; }
    #pragma unroll
    for (int s=0; s<2; s++){
      int koff = s*32 + quad*8;
      short8 a0 = ld_frag(sH + (r0+l15)*136 + koff*2);
      short8 a1 = ld_frag(sH + (r0+16+l15)*136 + koff*2);
      #pragma unroll
      for (int nf=0; nf<4; nf++){
        short8 b = ld_frag((const unsigned char*)wb9 + (16*nf+l15)*128 + koff*2);
        acc[0][nf] = mfma16(a0, b, acc[0][nf]);
        acc[1][nf] = mfma16(a1, b, acc[1][nf]);
      }
    }
    float part[2][4] = {{0.f,0.f,0.f,0.f},{0.f,0.f,0.f,0.f}};
    #pragma unroll
    for (int mf=0; mf<2; mf++)
      #pragma unroll
      for (int nf=0; nf<4; nf++){
        float w2 = Wv2[16*nf + l15];
        #pragma unroll
        for (int reg=0; reg<4; reg++)
          part[mf][reg] += silu_f(acc[mf][nf][reg]) * w2;
      }
    #pragma unroll
    for (int mf=0; mf<2; mf++)
      #pragma unroll
      for (int reg=0; reg<4; reg++){
        #pragma unroll
        for (int off=1; off<16; off<<=1)
          part[mf][reg] += __shfl_xor(part[mf][reg], off);
      }
    if (l15 == 0){
      #pragma unroll
      for (int mf=0; mf<2; mf++)
        #pragma unroll
        for (int reg=0; reg<4; reg++){
          int row = r0 + 16*mf + quad*4 + reg;
          int node = i0 + row;
          if (node < N_){
            float gate = 2.f/(1.f + __expf(-part[mf][reg]));
            float4 dvv = *(const float4*)(wsDv + (size_t)node*4);
            float dvs[3] = {dvv.x, dvv.y, dvv.z};
            #pragma unroll
            for (int ax=0; ax<3; ax++){
              float vn = gate * v[(size_t)node*3 + ax] + dvs[ax];
              out[(size_t)N_*64 + (size_t)node*3 + ax]                 = x[(size_t)node*3 + ax] + vn;
              out[(size_t)N_*64 + (size_t)N_*3 + (size_t)node*3 + ax]  = vn;
            }
          }
        }
    }
  }
}

// ---------------- launch ----------------
extern "C" void kernel_launch(void* const* d_in, const int* in_sizes, int n_in,
                              void* d_out, int out_size, void* d_ws, size_t ws_size,
                              hipStream_t stream)
{
  const float* h = (const float*)d_in[0];
  const float* x = (const float*)d_in[1];
  const float* v = (const float*)d_in[2];
  const int* idx_i = (const int*)d_in[3];
  const int* idx_j = (const int*)d_in[4];
  const float* Wein = (const float*)d_in[5];  const float* bein = (const float*)d_in[6];
  const float* Weo1 = (const float*)d_in[7];  const float* beo1 = (const float*)d_in[8];
  const float* Weo2 = (const float*)d_in[9];  const float* beo2 = (const float*)d_in[10];
  const float* Watt = (const float*)d_in[11]; const float* batt = (const float*)d_in[12];
  const float* Wxm  = (const float*)d_in[13]; const float* Wvm  = (const float*)d_in[14];
  const float* Wpn1 = (const float*)d_in[15]; const float* bpn1 = (const float*)d_in[16];
  const float* Wpn2 = (const float*)d_in[17]; const float* bpn2 = (const float*)d_in[18];
  const float* Wn1  = (const float*)d_in[19]; const float* bn1  = (const float*)d_in[20];
  const float* Wn2  = (const float*)d_in[21]; const float* bn2  = (const float*)d_in[22];
  const float* Wv1  = (const float*)d_in[23]; const float* bv1  = (const float*)d_in[24];
  const float* Wv2  = (const float*)d_in[25];

  float* wsf        = (float*)d_ws;
  int*   cnt        = (int*)(wsf + OFF_CNT);
  int*   offsets    = (int*)(wsf + OFF_OFFSETS);
  int*   cursor     = (int*)(wsf + OFF_CURSOR);
  int*   sorted     = (int*)(wsf + OFF_SORTED);
  unsigned int* edgeb = (unsigned int*)(wsf + OFF_EDGE);
  float* e4o        = wsf + OFF_E4;
  float* diro       = wsf + OFF_DIR;
  float* wsSem      = wsf + OFF_SEM;
  float* wsN2       = wsf + OFF_N2;
  float* wsDv       = wsf + OFF_DV;
  unsigned short* wb1 = (unsigned short*)(wsf + OFF_WB1);
  unsigned short* wb2 = (unsigned short*)(wsf + OFF_WB2);
  unsigned short* wb3 = (unsigned short*)(wsf + OFF_WB3);
  unsigned short* wb4 = (unsigned short*)(wsf + OFF_WB4);
  unsigned short* wb5 = (unsigned short*)(wsf + OFF_WB5);
  unsigned short* wb6 = (unsigned short*)(wsf + OFF_WB6);
  unsigned short* wb7 = (unsigned short*)(wsf + OFF_WB7);
  unsigned short* wb8 = (unsigned short*)(wsf + OFF_WB8);
  unsigned short* wb9 = (unsigned short*)(wsf + OFF_WB9);
  unsigned int*   hb  = (unsigned int*)(wsf + OFF_HB);

  hipMemsetAsync(cnt, 0, N_*sizeof(int), stream);
  k_hist<<<(P_+255)/256, 256, 0, stream>>>(idx_i, cnt);
  k_scan<<<1, 1024, 0, stream>>>(cnt, offsets, cursor);
  k_prepw<<<32, 256, 0, stream>>>(Wein, Weo1, Weo2, Wxm, Wpn1, Wpn2, Wn1, Wn2, Wv1,
                                  wb1, wb2, wb3, wb4, wb5, wb6, wb7, wb8, wb9);
  k_preph<<<(N_*32+255)/256, 256, 0, stream>>>(h, hb);
  k_scatter<<<(P_+255)/256, 256, 0, stream>>>(idx_i, cursor, sorted);
  k_edge2<<<P_/128, 256, 0, stream>>>((const unsigned short*)hb, x, idx_i, idx_j, sorted,
                                      wb1, wb2, wb3,
                                      bein, beo1, beo2, Watt, batt,
                                      edgeb, e4o, diro);
  k_agg<<<(N_+3)/4, 256, 0, stream>>>(offsets, edgeb, e4o, diro, wb4, Wvm,
                                      wsSem, wsN2, wsDv);
  k_mlp<<<(N_+127)/128, 256, 0, stream>>>(h, x, v, wsSem, wsN2, wsDv,
                                          wb5, wb6, wb7, wb8, wb9,
                                          bpn1, bpn2, bn1, bn2, bv1, Wv2,
                                          (float*)d_out);
}

// Round 10
// 377.119 us; speedup vs baseline: 1.1777x; 1.0242x over previous
//
#include <hip/hip_runtime.h>
#include <hip/hip_bf16.h>

#define DEV __device__ __forceinline__

constexpr int N_ = 25000;
constexpr int P_ = 400000;

// ---------------- ws layout (units of 4 bytes) ----------------
constexpr int align4(int xx){ return (xx+3)&~3; }
constexpr int OFF_CNT     = 0;                          // N ints
constexpr int OFF_OFFSETS = align4(OFF_CNT + N_);       // N+1 ints
constexpr int OFF_CURSOR  = align4(OFF_OFFSETS + N_ + 1);
constexpr int OFF_EDGE    = align4(OFF_CURSOR + N_);    // P*16 dwords (32 bf16 edge feats, sorted order)
constexpr int OFF_E4      = OFF_EDGE + P_*16;           // P*4  f32
constexpr int OFF_DIR     = OFF_E4 + P_*4;              // P*4  f32 (written by k_scatter2)
constexpr int OFF_SEM     = align4(OFF_DIR + P_*4);     // N*128 f32
constexpr int OFF_N2      = OFF_SEM + N_*128;           // N*32 f32
constexpr int OFF_DV      = OFF_N2 + N_*32;             // N*4 f32
constexpr int OFF_WB5     = OFF_DV + N_*4;              // wpn1T [64][32]  = 1024 dw
constexpr int OFF_WB6     = OFF_WB5 + 1024;             // wpn2T [64][64]  = 2048 dw
constexpr int OFF_WB7     = OFF_WB6 + 2048;             // wn1T  [64][256] = 8192 dw
constexpr int OFF_WB8     = OFF_WB7 + 8192;             // wn2T  [64][64]  = 2048 dw
constexpr int OFF_WB9     = OFF_WB8 + 2048;             // wv1T  [64][64]  = 2048 dw
constexpr int OFF_HB      = OFF_WB9 + 2048;             // h as bf16: N*32 dw
constexpr int OFF_SIJ     = OFF_HB + N_*32;             // sorted (i,j) pairs: P*2 ints
constexpr int OFF_WB1     = OFF_SIJ + P_*2;             // [128 n][128 k] bf16 = 8192 dw
constexpr int OFF_WB2     = OFF_WB1 + 8192;             // [64 n][64 k]  bf16 = 2048 dw
constexpr int OFF_WB3     = OFF_WB2 + 2048;             // [32 n][64 k]  bf16 = 1024 dw
constexpr int OFF_WB4     = OFF_WB3 + 1024;             // [128 n][32 k] bf16 (permuted cols)
constexpr int WS_UNITS    = OFF_WB4 + 2048;             // ~15.8M dw = 63 MB (<= 66 MB proven r1)

// PhysNet RBF constants (K=50, r_max=0.5)
constexpr float MU0F  = 0.60653065971263342f;               // exp(-0.5)
constexpr float DMUF  = (1.0f - 0.60653065971263342f) / 49.0f;
constexpr float BETAF = 1.0f / ((0.04f * (1.0f - 0.60653065971263342f)) *
                                (0.04f * (1.0f - 0.60653065971263342f)));
constexpr float EPSF  = 1e-8f;

DEV float u2f(unsigned int u){ union{unsigned int i; float f;} c; c.i=u; return c.f; }
DEV unsigned int f2b16(float f){
  __hip_bfloat16 b = __float2bfloat16(f);
  unsigned short s; __builtin_memcpy(&s, &b, 2);
  return (unsigned int)s;
}
DEV unsigned int pack2(float a, float b){ return f2b16(a) | (f2b16(b) << 16); }
DEV float silu_f(float v){ return v / (1.0f + __expf(-v)); }

using short8 = __attribute__((ext_vector_type(8))) short;   // 8 bf16 (4 VGPRs)
using f32x4  = __attribute__((ext_vector_type(4))) float;
union U4S8 { uint4 u; short8 s; };
DEV short8 ld_frag(const void* p){ U4S8 c; c.u = *(const uint4*)p; return c.s; }
DEV f32x4 mfma16(short8 a, short8 b, f32x4 c){
  return __builtin_amdgcn_mfma_f32_16x16x32_bf16(a, b, c, 0, 0, 0);
}

// ---------------- prep0: histogram + h->bf16 + weight transposes ----------------
__global__ void k_prep0(const int* __restrict__ idx_i,
                        const float* __restrict__ h,
                        const float* __restrict__ Wein, const float* __restrict__ Weo1,
                        const float* __restrict__ Weo2, const float* __restrict__ Wxm,
                        const float* __restrict__ Wpn1, const float* __restrict__ Wpn2,
                        const float* __restrict__ Wn1,  const float* __restrict__ Wn2,
                        const float* __restrict__ Wv1,
                        int* __restrict__ cnt, unsigned int* __restrict__ hb,
                        unsigned short* __restrict__ wb1, unsigned short* __restrict__ wb2,
                        unsigned short* __restrict__ wb3, unsigned short* __restrict__ wb4,
                        unsigned short* __restrict__ wb5, unsigned short* __restrict__ wb6,
                        unsigned short* __restrict__ wb7, unsigned short* __restrict__ wb8,
                        unsigned short* __restrict__ wb9){
  int t = blockIdx.x*256 + threadIdx.x;
  const int st = gridDim.x*256;
  if (t < P_) atomicAdd(&cnt[idx_i[t]], 1);
  for (int q=t; q<N_*32; q+=st){
    float2 a = *(const float2*)(h + (size_t)q*2);
    hb[q] = pack2(a.x, a.y);
  }
  for (int q=t; q<128*128; q+=st){
    int n=q>>7, k=q&127;
    float v = (n<50) ? Wein[k*50+n] : ((n<64) ? 0.f : Weo1[k*64+(n-64)]);
    wb1[q] = (unsigned short)f2b16(v);
  }
  for (int q=t; q<64*64; q+=st){
    int n=q>>6, k=q&63;
    float v = (k<50) ? Weo1[(128+k)*64+n] : ((k==50) ? Weo1[178*64+n] : 0.f);
    wb2[q] = (unsigned short)f2b16(v);
  }
  for (int q=t; q<32*64; q+=st){
    int n=q>>6, k=q&63;
    wb3[q] = (unsigned short)f2b16(Weo2[k*32+n]);
  }
  // wb4 PERMUTED columns: physical col n_phys holds logical n = (n_phys&15)*8 + (n_phys>>4)
  // logical n = 4c+h -> value Wxm[(k*4+h)*32 + c]
  for (int q=t; q<128*32; q+=st){
    int n_phys=q>>5, k=q&31;
    int n_log = (n_phys & 15)*8 + (n_phys >> 4);
    int cc = n_log>>2, hh = n_log&3;
    wb4[q] = (unsigned short)f2b16(Wxm[(k*4+hh)*32 + cc]);
  }
  for (int q=t; q<64*32; q+=st){ int n=q>>5, k=q&31;  wb5[q] = (unsigned short)f2b16(Wpn1[k*64+n]); }
  for (int q=t; q<64*64; q+=st){ int n=q>>6, k=q&63;  wb6[q] = (unsigned short)f2b16(Wpn2[k*64+n]); }
  for (int q=t; q<64*256;q+=st){ int n=q>>8, k=q&255; wb7[q] = (unsigned short)f2b16(Wn1[k*64+n]); }
  for (int q=t; q<64*64; q+=st){ int n=q>>6, k=q&63;  wb8[q] = (unsigned short)f2b16(Wn2[k*64+n]); }
  for (int q=t; q<64*64; q+=st){ int n=q>>6, k=q&63;  wb9[q] = (unsigned short)f2b16(Wv1[k*64+n]); }
}

// ---------------- scan (2-barrier) ----------------
__global__ __launch_bounds__(1024) void k_scan(const int* __restrict__ cnt,
                                               int* __restrict__ offsets,
                                               int* __restrict__ cursor){
  __shared__ int swv[16];
  const int t = threadIdx.x;
  const int wv = t >> 6, ln = t & 63;
  constexpr int CH = (N_ + 1023)/1024;   // 25
  int b = t*CH, e = b+CH;
  if (b > N_) b = N_;
  if (e > N_) e = N_;
  int s = 0;
  for (int q=b; q<e; q++) s += cnt[q];
  int incl = s;
  #pragma unroll
  for (int off=1; off<64; off<<=1){
    int vv = __shfl_up(incl, off);
    if (ln >= off) incl += vv;
  }
  if (ln == 63) swv[wv] = incl;
  __syncthreads();
  if (wv == 0 && ln < 16){
    int w = swv[ln];
    #pragma unroll
    for (int off=1; off<16; off<<=1){
      int vv = __shfl_up(w, off);
      if (ln >= off) w += vv;
    }
    swv[ln] = w;
  }
  __syncthreads();
  const int wpre = (wv > 0) ? swv[wv-1] : 0;
  int run = wpre + incl - s;
  for (int q=b; q<e; q++){ offsets[q] = run; cursor[q] = run; run += cnt[q]; }
  if (t == 1023) offsets[N_] = run;
}

// ---------------- scatter + fused geometry ----------------
// Writes sorted (i,j) pairs AND dir4 (dirx,diry,dirz,d) at the sorted position —
// removes the sorted->idx->x double indirection from k_edge's critical path.
__global__ void k_scatter2(const int* __restrict__ idx_i, const int* __restrict__ idx_j,
                           const float* __restrict__ x,
                           int* __restrict__ cursor,
                           int* __restrict__ sij, float* __restrict__ dir4){
  int t = blockIdx.x*256 + threadIdx.x;
  if (t >= P_) return;
  int i = idx_i[t], j = idx_j[t];
  int pos = atomicAdd(&cursor[i], 1);
  *(int2*)(sij + (size_t)pos*2) = make_int2(i, j);
  float xi0=x[i*3], xi1=x[i*3+1], xi2=x[i*3+2];
  float xj0=x[j*3], xj1=x[j*3+1], xj2=x[j*3+2];
  float rx=xj0-xi0, ry=xj1-xi1, rz=xj2-xi2;
  float d = sqrtf(rx*rx+ry*ry+rz*rz+EPSF);
  float iv = 1.0f/(d+EPSF);
  *(float4*)(dir4 + (size_t)pos*4) = make_float4(rx*iv, ry*iv, rz*iv, d);
}

// ---------------- MFMA edge kernel: short chain head, low-AGPR split ----------------
__global__ __launch_bounds__(256, 4) void k_edge2(
    const unsigned short* __restrict__ hb,
    const int* __restrict__ sij, const float* __restrict__ dir4,
    const unsigned short* __restrict__ wb1, const unsigned short* __restrict__ wb2,
    const unsigned short* __restrict__ wb3,
    const float* __restrict__ bein, const float* __restrict__ beo1,
    const float* __restrict__ beo2, const float* __restrict__ Watt,
    const float* __restrict__ batt,
    unsigned int* __restrict__ edge_out, float* __restrict__ e4_out)
{
  __shared__ __align__(16) unsigned char sAll[4*9216];   // 36864 B
  __shared__ float sdv[128];
  __shared__ float semd[128];

  const int tid  = threadIdx.x;
  const int wv   = tid >> 6;
  const int lane = tid & 63;
  const int l15  = lane & 15;
  const int quad = lane >> 4;
  const int pbase = blockIdx.x * 128;
  unsigned char* sW = sAll + wv*9216;

  // ---- geometry: contiguous dir4 read (lanes 0..31) ----
  if (lane < 32){
    int row = 32*wv + lane;
    float4 dv = *(const float4*)(dir4 + (size_t)(pbase + row)*4);
    sdv[row] = dv.w;
    semd[row] = __expf(-dv.w);
  }

  // ---- stage A1 = hcat bf16 (2 threads/row; one int2 load then 128 B copy) ----
  {
    int rr = lane >> 1;
    int2 ij = *(const int2*)(sij + (size_t)(pbase + 32*wv + rr)*2);
    int hidx = (lane & 1) ? ij.y : ij.x;
    const uint4* hp = (const uint4*)(hb + (size_t)hidx*64);
    unsigned char* dst = sW + rr*264 + (lane&1)*128;
    #pragma unroll
    for (int q=0;q<8;q++) *(uint4*)(dst + q*16) = hp[q];
  }

  // ---- load all A-fragments into registers ----
  short8 af0[4], af1[4];
  #pragma unroll
  for (int s=0; s<4; s++){
    int koff = s*32 + quad*8;
    af0[s] = ld_frag(sW + l15*264      + koff*2);
    af1[s] = ld_frag(sW + (16+l15)*264 + koff*2);
  }

  // ---- GEMM-1a: [32 x 128] @ WB1[:, 0..63] (Wein) ----
  f32x4 acc[2][4];
  #pragma unroll
  for (int mf=0; mf<2; mf++)
    #pragma unroll
    for (int nf=0; nf<4; nf++){
      int nn = 16*nf + l15;
      float bias = (nn < 50) ? bein[nn] : 0.f;
      acc[mf][nf] = (f32x4){bias, bias, bias, bias};
    }
  #pragma unroll
  for (int s=0; s<4; s++){
    int koff = s*32 + quad*8;
    #pragma unroll
    for (int nf=0; nf<4; nf++){
      short8 b = ld_frag((const unsigned char*)wb1 + (16*nf + l15)*256 + koff*2);
      acc[0][nf] = mfma16(af0[s], b, acc[0][nf]);
      acc[1][nf] = mfma16(af1[s], b, acc[1][nf]);
    }
  }

  // ---- epilogue 1: RBF -> A2 bf16 [lrow][72 ushort] at sW+0 ----
  #pragma unroll
  for (int mf=0; mf<2; mf++)
    #pragma unroll
    for (int nf=0; nf<4; nf++){
      int n = 16*nf + l15;
      float mu = MU0F + (float)n*DMUF;
      #pragma unroll
      for (int reg=0; reg<4; reg++){
        int lrow = 16*mf + quad*4 + reg;
        int grow = 32*wv + lrow;
        float t = semd[grow] - mu;
        float fv = acc[mf][nf][reg] * __expf(-BETAF*t*t);
        unsigned short ob;
        if (n < 50)       ob = (unsigned short)f2b16(fv);
        else if (n == 50) ob = (unsigned short)f2b16(sdv[grow]);
        else              ob = 0;
        ((unsigned short*)sW)[lrow*72 + n] = ob;
      }
    }

  // ---- GEMM-1b: @ WB1[:, 64..127] (Weo1-top) into reused acc ----
  #pragma unroll
  for (int mf=0; mf<2; mf++)
    #pragma unroll
    for (int nf=0; nf<4; nf++){
      float bias = beo1[16*nf + l15];
      acc[mf][nf] = (f32x4){bias, bias, bias, bias};
    }
  #pragma unroll
  for (int s=0; s<4; s++){
    int koff = s*32 + quad*8;
    #pragma unroll
    for (int nf=0; nf<4; nf++){
      short8 b = ld_frag((const unsigned char*)wb1 + (64 + 16*nf + l15)*256 + koff*2);
      acc[0][nf] = mfma16(af0[s], b, acc[0][nf]);
      acc[1][nf] = mfma16(af1[s], b, acc[1][nf]);
    }
  }

  // ---- GEMM-2: += A2 [32 x 64] @ WB2 [64 x 64] ----
  #pragma unroll
  for (int s=0; s<2; s++){
    int koff = s*32 + quad*8;
    short8 a0 = ld_frag(sW + l15*144      + koff*2);
    short8 a1 = ld_frag(sW + (16+l15)*144 + koff*2);
    #pragma unroll
    for (int nf=0; nf<4; nf++){
      short8 b = ld_frag((const unsigned char*)wb2 + (16*nf + l15)*128 + koff*2);
      acc[0][nf] = mfma16(a0, b, acc[0][nf]);
      acc[1][nf] = mfma16(a1, b, acc[1][nf]);
    }
  }

  // ---- epilogue 2: silu -> A3 bf16 at sW+4608 ----
  unsigned char* A3 = sW + 4608;
  #pragma unroll
  for (int mf=0; mf<2; mf++)
    #pragma unroll
    for (int nf=0; nf<4; nf++){
      int n = 16*nf + l15;
      #pragma unroll
      for (int reg=0; reg<4; reg++){
        int lrow = 16*mf + quad*4 + reg;
        ((unsigned short*)A3)[lrow*72 + n] = (unsigned short)f2b16(silu_f(acc[mf][nf][reg]));
      }
    }

  // ---- GEMM-3: [32 x 64] @ WB3 [64 x 32] ----
  f32x4 acc3[2][2];
  #pragma unroll
  for (int mf=0; mf<2; mf++)
    #pragma unroll
    for (int nf=0; nf<2; nf++){
      float bias = beo2[16*nf + l15];
      acc3[mf][nf] = (f32x4){bias, bias, bias, bias};
    }
  #pragma unroll
  for (int s=0; s<2; s++){
    int koff = s*32 + quad*8;
    short8 a0 = ld_frag(A3 + l15*144      + koff*2);
    short8 a1 = ld_frag(A3 + (16+l15)*144 + koff*2);
    #pragma unroll
    for (int nf=0; nf<2; nf++){
      short8 b = ld_frag((const unsigned char*)wb3 + (16*nf + l15)*128 + koff*2);
      acc3[0][nf] = mfma16(a0, b, acc3[0][nf]);
      acc3[1][nf] = mfma16(a1, b, acc3[1][nf]);
    }
  }

  // ---- epilogue 3: C3 f32 [lrow][36 f32] at sW+0 ----
  #pragma unroll
  for (int mf=0; mf<2; mf++)
    #pragma unroll
    for (int nf=0; nf<2; nf++){
      int n = 16*nf + l15;
      #pragma unroll
      for (int reg=0; reg<4; reg++){
        int lrow = 16*mf + quad*4 + reg;
        ((float*)sW)[lrow*36 + n] = acc3[mf][nf][reg];
      }
    }

  // ---- attention + stores (2 lanes per row) ----
  {
    int rr = lane >> 1;
    int p = pbase + 32*wv + rr;
    int cb = (lane & 1) * 16;
    const float* er = (const float*)(sW + rr*144);
    float l0, l1, l2, l3;
    if ((lane & 1) == 0){ l0 = batt[0]; l1 = batt[1]; l2 = batt[2]; l3 = batt[3]; }
    else                { l0 = l1 = l2 = l3 = 0.f; }
    float ecache[16];
    #pragma unroll
    for (int c=0;c<16;c++){
      float ev = er[cb + c];
      ecache[c] = ev;
      const float4 wr = *(const float4*)(Watt + (cb + c)*4);
      l0 += ev*wr.x; l1 += ev*wr.y; l2 += ev*wr.z; l3 += ev*wr.w;
    }
    l0 += __shfl_xor(l0,1); l1 += __shfl_xor(l1,1);
    l2 += __shfl_xor(l2,1); l3 += __shfl_xor(l3,1);
    if ((lane & 1) == 0){
      float e0 = __expf(l0 > 0.f ? l0 : 2.f*(__expf(l0*0.5f)-1.f));
      float e1 = __expf(l1 > 0.f ? l1 : 2.f*(__expf(l1*0.5f)-1.f));
      float e2 = __expf(l2 > 0.f ? l2 : 2.f*(__expf(l2*0.5f)-1.f));
      float e3 = __expf(l3 > 0.f ? l3 : 2.f*(__expf(l3*0.5f)-1.f));
      *(float4*)(e4_out + (size_t)p*4) = make_float4(e0, e1, e2, e3);
    }
    uint4 o1 = make_uint4(pack2(ecache[0],ecache[1]),  pack2(ecache[2],ecache[3]),
                          pack2(ecache[4],ecache[5]),  pack2(ecache[6],ecache[7]));
    uint4 o2 = make_uint4(pack2(ecache[8],ecache[9]),  pack2(ecache[10],ecache[11]),
                          pack2(ecache[12],ecache[13]),pack2(ecache[14],ecache[15]));
    unsigned int* ep = edge_out + (size_t)p*16 + (lane&1)*8;
    *(uint4*)(ep)     = o1;
    *(uint4*)(ep + 4) = o2;
  }
}

// ---------------- aggregation: 1 node/wave, b128 writeback, prefetched inner ----------
__global__ __launch_bounds__(256, 4) void k_agg(
    const int* __restrict__ offsets,
    const unsigned int* __restrict__ edgeb,
    const float* __restrict__ e4,
    const float* __restrict__ dir4,
    const unsigned short* __restrict__ wb4,
    const float* __restrict__ Wvm,
    float* __restrict__ wsSem, float* __restrict__ wsN2, float* __restrict__ wsDv)
{
  __shared__ __align__(16) unsigned char sAllB[4*10240];
  const int wv   = threadIdx.x >> 6;
  const int lane = threadIdx.x & 63;
  unsigned char* sA = sAllB + wv*10240;
  unsigned char* gC = sA + 2048;

  const int c    = lane & 31;
  const int l15  = lane & 15;
  const int quad = lane >> 4;
  const int half = lane >> 5;
  const bool low = (lane < 32);

  short8 b4[8];
  #pragma unroll
  for (int nf=0; nf<8; nf++)
    b4[nf] = ld_frag((const unsigned char*)wb4 + (16*nf + l15)*64 + quad*16);
  const float wvm_c = Wvm[c];

  const int i = blockIdx.x*4 + wv;
  if (i >= N_) return;
  const int n0 = offsets[i], n1 = offsets[i+1];
  const int cnt = n1 - n0;

  // first-chunk staging before the denominator pass (independent streams)
  {
    const int nc0 = min(32, cnt);
    if (lane*32 < nc0*64){
      const uint4* src = (const uint4*)(edgeb + (size_t)n0*16 + lane*8);
      *(uint4*)(sA + lane*32)      = src[0];
      *(uint4*)(sA + lane*32 + 16) = src[1];
    }
  }

  float d0=0.f,d1=0.f,d2=0.f,d3=0.f;
  for (int s = n0 + lane; s < n1; s += 64){
    const float4 ev = *(const float4*)(e4 + (size_t)s*4);
    d0+=ev.x; d1+=ev.y; d2+=ev.z; d3+=ev.w;
  }
  #pragma unroll
  for (int off=32; off>=1; off>>=1){
    d0 += __shfl_xor(d0,off); d1 += __shfl_xor(d1,off);
    d2 += __shfl_xor(d2,off); d3 += __shfl_xor(d3,off);
  }
  const float i0 = (cnt>0)?1.f/d0:0.f, i1 = (cnt>0)?1.f/d1:0.f;
  const float i2 = (cnt>0)?1.f/d2:0.f, i3 = (cnt>0)?1.f/d3:0.f;

  float sem4[4] = {0.f,0.f,0.f,0.f};
  float cx=0.f,cy=0.f,cz=0.f, gx=0.f,gy=0.f,gz=0.f;

  bool staged = true;                    // first chunk already staged
  for (int base = n0; base < n1; base += 32){
    const int nc = min(32, n1 - base);
    if (!staged){
      if (lane*32 < nc*64){
        const uint4* src = (const uint4*)(edgeb + (size_t)base*16 + lane*8);
        *(uint4*)(sA + lane*32)      = src[0];
        *(uint4*)(sA + lane*32 + 16) = src[1];
      }
    }
    staged = false;
    // half 0: rows 0..15 — compute then b128 writeback (wb4 cols permuted so
    // lane's 8 nf-values are contiguous logical n = l15*8 + nf)
    {
      short8 a0 = ld_frag(sA + l15*64 + quad*16);
      f32x4 accg[8];
      #pragma unroll
      for (int nf=0; nf<8; nf++){
        f32x4 z = (f32x4){0.f,0.f,0.f,0.f};
        accg[nf] = mfma16(a0, b4[nf], z);
      }
      #pragma unroll
      for (int reg=0; reg<4; reg++){
        int row = quad*4 + reg;
        uint4 o = make_uint4(pack2(accg[0][reg],accg[1][reg]),
                             pack2(accg[2][reg],accg[3][reg]),
                             pack2(accg[4][reg],accg[5][reg]),
                             pack2(accg[6][reg],accg[7][reg]));
        *(uint4*)(gC + row*256 + l15*16) = o;
      }
    }
    // half 1: rows 16..31
    if (nc > 16){
      short8 a1 = ld_frag(sA + (16+l15)*64 + quad*16);
      f32x4 accg[8];
      #pragma unroll
      for (int nf=0; nf<8; nf++){
        f32x4 z = (f32x4){0.f,0.f,0.f,0.f};
        accg[nf] = mfma16(a1, b4[nf], z);
      }
      #pragma unroll
      for (int reg=0; reg<4; reg++){
        int row = 16 + quad*4 + reg;
        uint4 o = make_uint4(pack2(accg[0][reg],accg[1][reg]),
                             pack2(accg[2][reg],accg[3][reg]),
                             pack2(accg[4][reg],accg[5][reg]),
                             pack2(accg[6][reg],accg[7][reg]));
        *(uint4*)(gC + row*256 + l15*16) = o;
      }
    }
    // inner: 2 pairs/iter, next iteration's e4/dir4 prefetched into regs
    float4 evc, dvc;
    {
      int s0 = base + min(half, nc-1);
      evc = *(const float4*)(e4 + (size_t)s0*4);
      dvc = *(const float4*)(dir4 + (size_t)s0*4);
    }
    for (int t0 = 0; t0 < nc; t0 += 2){
      const float4 ev = evc, dv = dvc;
      const int nt = t0 + 2 + half;
      if (nt < nc){
        int s2 = base + nt;
        evc = *(const float4*)(e4 + (size_t)s2*4);
        dvc = *(const float4*)(dir4 + (size_t)s2*4);
      }
      const int rloc = t0 + half;
      const bool act = rloc < nc;
      const float aw0 = ev.x*i0, aw1 = ev.y*i1, aw2 = ev.z*i2, aw3 = ev.w*i3;
      uint2 gv = *(const uint2*)(gC + rloc*256 + c*8);
      float g0=u2f(gv.x<<16), g1=u2f(gv.x&0xffff0000u);
      float g2=u2f(gv.y<<16), g3=u2f(gv.y&0xffff0000u);
      float tp = aw0*g0 + aw1*g1 + aw2*g2 + aw3*g3;
      float tt = fminf(fmaxf(tp, -15.f), 15.f);
      float ex = __expf(2.f*tt);
      float th = (ex-1.f)/(ex+1.f);
      unsigned int ew = *(const unsigned int*)(sA + rloc*64 + (c>>1)*4);
      float ec = (c & 1) ? u2f(ew & 0xffff0000u) : u2f(ew << 16);
      if (act){
        sem4[0] += ec*aw0; sem4[1] += ec*aw1;
        sem4[2] += ec*aw2; sem4[3] += ec*aw3;
        cx += th*dv.x; cy += th*dv.y; cz += th*dv.z;
        float tw = th*wvm_c;
        gx += tw*dv.x; gy += tw*dv.y; gz += tw*dv.z;
      }
    }
  }

  #pragma unroll
  for (int j=0;j<4;j++) sem4[j] += __shfl_xor(sem4[j], 32);
  cx += __shfl_xor(cx,32); cy += __shfl_xor(cy,32); cz += __shfl_xor(cz,32);
  #pragma unroll
  for (int off=32; off>=1; off>>=1){
    gx += __shfl_xor(gx,off); gy += __shfl_xor(gy,off); gz += __shfl_xor(gz,off);
  }
  const float invc = 1.f/(float)(cnt > 1 ? cnt : 1);
  if (low){
    float mx = cx*invc, my = cy*invc, mz = cz*invc;
    wsN2[(size_t)i*32 + c] = mx*mx + my*my + mz*mz;
    *(float4*)(wsSem + (size_t)i*128 + 4*c) = make_float4(sem4[0], sem4[1], sem4[2], sem4[3]);
  }
  if (lane == 0)
    *(float4*)(wsDv + (size_t)i*4) = make_float4(gx*invc, gy*invc, gz*invc, 0.f);
}

// ---------------- node MLP kernel: batched MFMA GEMM, 128 nodes/block ----------------
__global__ __launch_bounds__(256) void k_mlp(
    const float* __restrict__ h, const float* __restrict__ x, const float* __restrict__ v,
    const float* __restrict__ wsSem, const float* __restrict__ wsN2,
    const float* __restrict__ wsDv,
    const unsigned short* __restrict__ wb5, const unsigned short* __restrict__ wb6,
    const unsigned short* __restrict__ wb7, const unsigned short* __restrict__ wb8,
    const unsigned short* __restrict__ wb9,
    const float* __restrict__ bpn1, const float* __restrict__ bpn2,
    const float* __restrict__ bn1,  const float* __restrict__ bn2,
    const float* __restrict__ bv1,  const float* __restrict__ Wv2,
    float* __restrict__ out)
{
  __shared__ __align__(16) unsigned char sH[128*136];
  __shared__ __align__(16) unsigned char sSem[128*264];
  __shared__ __align__(16) unsigned char sSp[128*136];
  __shared__ __align__(16) unsigned char sN2[128*72];
  __shared__ __align__(16) unsigned char sTmp[128*136];

  const int tid  = threadIdx.x;
  const int wv   = tid >> 6;
  const int lane = tid & 63;
  const int l15  = lane & 15;
  const int quad = lane >> 4;
  const int i0   = blockIdx.x*128;
  const int r0   = 32*wv;

  for (int idx = tid; idx < 128*16; idx += 256){
    int row = idx >> 4, c4 = idx & 15;
    int node = min(i0 + row, N_-1);
    float4 a = *(const float4*)(h + (size_t)node*64 + c4*4);
    *(uint2*)(sH + row*136 + c4*8) = make_uint2(pack2(a.x,a.y), pack2(a.z,a.w));
  }
  for (int idx = tid; idx < 128*32; idx += 256){
    int row = idx >> 5, c4 = idx & 31;
    int node = min(i0 + row, N_-1);
    float4 a = *(const float4*)(wsSem + (size_t)node*128 + c4*4);
    *(uint2*)(sSem + row*264 + c4*8) = make_uint2(pack2(a.x,a.y), pack2(a.z,a.w));
  }
  for (int idx = tid; idx < 128*8; idx += 256){
    int row = idx >> 3, c4 = idx & 7;
    int node = min(i0 + row, N_-1);
    float4 a = *(const float4*)(wsN2 + (size_t)node*32 + c4*4);
    *(uint2*)(sN2 + row*72 + c4*8) = make_uint2(pack2(a.x,a.y), pack2(a.z,a.w));
  }
  __syncthreads();

  // S1
  {
    f32x4 acc[2][4];
    #pragma unroll
    for (int mf=0; mf<2; mf++)
      #pragma unroll
      for (int nf=0; nf<4; nf++){ float b = bpn1[16*nf+l15]; acc[mf][nf] = (f32x4){b,b,b,b}; }
    short8 a0 = ld_frag(sN2 + (r0+l15)*72 + quad*16);
    short8 a1 = ld_frag(sN2 + (r0+16+l15)*72 + quad*16);
    #pragma unroll
    for (int nf=0; nf<4; nf++){
      short8 b = ld_frag((const unsigned char*)wb5 + (16*nf+l15)*64 + quad*16);
      acc[0][nf] = mfma16(a0, b, acc[0][nf]);
      acc[1][nf] = mfma16(a1, b, acc[1][nf]);
    }
    #pragma unroll
    for (int mf=0; mf<2; mf++)
      #pragma unroll
      for (int nf=0; nf<4; nf++){
        int n = 16*nf + l15;
        #pragma unroll
        for (int reg=0; reg<4; reg++){
          int row = r0 + 16*mf + quad*4 + reg;
          ((unsigned short*)(sTmp + row*136))[n] = (unsigned short)f2b16(silu_f(acc[mf][nf][reg]));
        }
      }
  }
  // S2
  {
    f32x4 acc[2][4];
    #pragma unroll
    for (int mf=0; mf<2; mf++)
      #pragma unroll
      for (int nf=0; nf<4; nf++){ float b = bpn2[16*nf+l15]; acc[mf][nf] = (f32x4){b,b,b,b}; }
    #pragma unroll
    for (int s=0; s<2; s++){
      int koff = s*32 + quad*8;
      short8 a0 = ld_frag(sTmp + (r0+l15)*136 + koff*2);
      short8 a1 = ld_frag(sTmp + (r0+16+l15)*136 + koff*2);
      #pragma unroll
      for (int nf=0; nf<4; nf++){
        short8 b = ld_frag((const unsigned char*)wb6 + (16*nf+l15)*128 + koff*2);
        acc[0][nf] = mfma16(a0, b, acc[0][nf]);
        acc[1][nf] = mfma16(a1, b, acc[1][nf]);
      }
    }
    #pragma unroll
    for (int mf=0; mf<2; mf++)
      #pragma unroll
      for (int nf=0; nf<4; nf++){
        int n = 16*nf + l15;
        #pragma unroll
        for (int reg=0; reg<4; reg++){
          int row = r0 + 16*mf + quad*4 + reg;
          ((unsigned short*)(sSp + row*136))[n] = (unsigned short)f2b16(silu_f(acc[mf][nf][reg]));
        }
      }
  }
  // N1 (K=256)
  {
    f32x4 acc[2][4];
    #pragma unroll
    for (int mf=0; mf<2; mf++)
      #pragma unroll
      for (int nf=0; nf<4; nf++){ float b = bn1[16*nf+l15]; acc[mf][nf] = (f32x4){b,b,b,b}; }
    #pragma unroll
    for (int s=0; s<8; s++){
      int koff = s*32 + quad*8;
      const unsigned char *pa0, *pa1;
      if (koff < 64){ pa0 = sH + (r0+l15)*136 + koff*2;          pa1 = sH + (r0+16+l15)*136 + koff*2; }
      else if (koff < 192){ pa0 = sSem + (r0+l15)*264 + (koff-64)*2;  pa1 = sSem + (r0+16+l15)*264 + (koff-64)*2; }
      else { pa0 = sSp + (r0+l15)*136 + (koff-192)*2;            pa1 = sSp + (r0+16+l15)*136 + (koff-192)*2; }
      short8 a0 = ld_frag(pa0);
      short8 a1 = ld_frag(pa1);
      #pragma unroll
      for (int nf=0; nf<4; nf++){
        short8 b = ld_frag((const unsigned char*)wb7 + (16*nf+l15)*512 + koff*2);
        acc[0][nf] = mfma16(a0, b, acc[0][nf]);
        acc[1][nf] = mfma16(a1, b, acc[1][nf]);
      }
    }
    #pragma unroll
    for (int mf=0; mf<2; mf++)
      #pragma unroll
      for (int nf=0; nf<4; nf++){
        int n = 16*nf + l15;
        #pragma unroll
        for (int reg=0; reg<4; reg++){
          int row = r0 + 16*mf + quad*4 + reg;
          ((unsigned short*)(sTmp + row*136))[n] = (unsigned short)f2b16(silu_f(acc[mf][nf][reg]));
        }
      }
  }
  // N2 + residual
  {
    f32x4 acc[2][4];
    #pragma unroll
    for (int mf=0; mf<2; mf++)
      #pragma unroll
      for (int nf=0; nf<4; nf++){ float b = bn2[16*nf+l15]; acc[mf][nf] = (f32x4){b,b,b,b}; }
    #pragma unroll
    for (int s=0; s<2; s++){
      int koff = s*32 + quad*8;
      short8 a0 = ld_frag(sTmp + (r0+l15)*136 + koff*2);
      short8 a1 = ld_frag(sTmp + (r0+16+l15)*136 + koff*2);
      #pragma unroll
      for (int nf=0; nf<4; nf++){
        short8 b = ld_frag((const unsigned char*)wb8 + (16*nf+l15)*128 + koff*2);
        acc[0][nf] = mfma16(a0, b, acc[0][nf]);
        acc[1][nf] = mfma16(a1, b, acc[1][nf]);
      }
    }
    #pragma unroll
    for (int mf=0; mf<2; mf++)
      #pragma unroll
      for (int nf=0; nf<4; nf++){
        int n = 16*nf + l15;
        #pragma unroll
        for (int reg=0; reg<4; reg++){
          int row = r0 + 16*mf + quad*4 + reg;
          int node = i0 + row;
          float hv = (node < N_) ? h[(size_t)node*64 + n] : 0.f;
          float hnew = hv + silu_f(acc[mf][nf][reg]);
          if (node < N_) out[(size_t)node*64 + n] = hnew;
          ((unsigned short*)(sH + row*136))[n] = (unsigned short)f2b16(hnew);
        }
      }
  }
  // V1 + gate + v/x
  {
    f32x4 acc[2][4];
    #pragma unroll
    for (int mf=0; mf<2; mf++)
      #pragma unroll
      for (int nf=0; nf<4; nf++){ float b = bv1[16*nf+l15]; acc[mf][nf] = (f32x4){b,b,b,b}; }
    #pragma unroll
    for (int s=0; s<2; s++){
      int koff = s*32 + quad*8;
      short8 a0 = ld_frag(sH + (r0+l15)*136 + koff*2);
      short8 a1 = ld_frag(sH + (r0+16+l15)*136 + koff*2);
      #pragma unroll
      for (int nf=0; nf<4; nf++){
        short8 b = ld_frag((const unsigned char*)wb9 + (16*nf+l15)*128 + koff*2);
        acc[0][nf] = mfma16(a0, b, acc[0][nf]);
        acc[1][nf] = mfma16(a1, b, acc[1][nf]);
      }
    }
    float part[2][4] = {{0.f,0.f,0.f,0.f},{0.f,0.f,0.f,0.f}};
    #pragma unroll
    for (int mf=0; mf<2; mf++)
      #pragma unroll
      for (int nf=0; nf<4; nf++){
        float w2 = Wv2[16*nf + l15];
        #pragma unroll
        for (int reg=0; reg<4; reg++)
          part[mf][reg] += silu_f(acc[mf][nf][reg]) * w2;
      }
    #pragma unroll
    for (int mf=0; mf<2; mf++)
      #pragma unroll
      for (int reg=0; reg<4; reg++){
        #pragma unroll
        for (int off=1; off<16; off<<=1)
          part[mf][reg] += __shfl_xor(part[mf][reg], off);
      }
    if (l15 == 0){
      #pragma unroll
      for (int mf=0; mf<2; mf++)
        #pragma unroll
        for (int reg=0; reg<4; reg++){
          int row = r0 + 16*mf + quad*4 + reg;
          int node = i0 + row;
          if (node < N_){
            float gate = 2.f/(1.f + __expf(-part[mf][reg]));
            float4 dvv = *(const float4*)(wsDv + (size_t)node*4);
            float dvs[3] = {dvv.x, dvv.y, dvv.z};
            #pragma unroll
            for (int ax=0; ax<3; ax++){
              float vn = gate * v[(size_t)node*3 + ax] + dvs[ax];
              out[(size_t)N_*64 + (size_t)node*3 + ax]                 = x[(size_t)node*3 + ax] + vn;
              out[(size_t)N_*64 + (size_t)N_*3 + (size_t)node*3 + ax]  = vn;
            }
          }
        }
    }
  }
}

// ---------------- launch ----------------
extern "C" void kernel_launch(void* const* d_in, const int* in_sizes, int n_in,
                              void* d_out, int out_size, void* d_ws, size_t ws_size,
                              hipStream_t stream)
{
  const float* h = (const float*)d_in[0];
  const float* x = (const float*)d_in[1];
  const float* v = (const float*)d_in[2];
  const int* idx_i = (const int*)d_in[3];
  const int* idx_j = (const int*)d_in[4];
  const float* Wein = (const float*)d_in[5];  const float* bein = (const float*)d_in[6];
  const float* Weo1 = (const float*)d_in[7];  const float* beo1 = (const float*)d_in[8];
  const float* Weo2 = (const float*)d_in[9];  const float* beo2 = (const float*)d_in[10];
  const float* Watt = (const float*)d_in[11]; const float* batt = (const float*)d_in[12];
  const float* Wxm  = (const float*)d_in[13]; const float* Wvm  = (const float*)d_in[14];
  const float* Wpn1 = (const float*)d_in[15]; const float* bpn1 = (const float*)d_in[16];
  const float* Wpn2 = (const float*)d_in[17]; const float* bpn2 = (const float*)d_in[18];
  const float* Wn1  = (const float*)d_in[19]; const float* bn1  = (const float*)d_in[20];
  const float* Wn2  = (const float*)d_in[21]; const float* bn2  = (const float*)d_in[22];
  const float* Wv1  = (const float*)d_in[23]; const float* bv1  = (const float*)d_in[24];
  const float* Wv2  = (const float*)d_in[25];

  float* wsf        = (float*)d_ws;
  int*   cnt        = (int*)(wsf + OFF_CNT);
  int*   offsets    = (int*)(wsf + OFF_OFFSETS);
  int*   cursor     = (int*)(wsf + OFF_CURSOR);
  unsigned int* edgeb = (unsigned int*)(wsf + OFF_EDGE);
  float* e4o        = wsf + OFF_E4;
  float* diro       = wsf + OFF_DIR;
  float* wsSem      = wsf + OFF_SEM;
  float* wsN2       = wsf + OFF_N2;
  float* wsDv       = wsf + OFF_DV;
  unsigned short* wb1 = (unsigned short*)(wsf + OFF_WB1);
  unsigned short* wb2 = (unsigned short*)(wsf + OFF_WB2);
  unsigned short* wb3 = (unsigned short*)(wsf + OFF_WB3);
  unsigned short* wb4 = (unsigned short*)(wsf + OFF_WB4);
  unsigned short* wb5 = (unsigned short*)(wsf + OFF_WB5);
  unsigned short* wb6 = (unsigned short*)(wsf + OFF_WB6);
  unsigned short* wb7 = (unsigned short*)(wsf + OFF_WB7);
  unsigned short* wb8 = (unsigned short*)(wsf + OFF_WB8);
  unsigned short* wb9 = (unsigned short*)(wsf + OFF_WB9);
  unsigned int*   hb  = (unsigned int*)(wsf + OFF_HB);
  int*            sij = (int*)(wsf + OFF_SIJ);

  hipMemsetAsync(cnt, 0, N_*sizeof(int), stream);
  k_prep0<<<(P_+255)/256, 256, 0, stream>>>(idx_i, h, Wein, Weo1, Weo2, Wxm,
                                            Wpn1, Wpn2, Wn1, Wn2, Wv1,
                                            cnt, hb, wb1, wb2, wb3, wb4,
                                            wb5, wb6, wb7, wb8, wb9);
  k_scan<<<1, 1024, 0, stream>>>(cnt, offsets, cursor);
  k_scatter2<<<(P_+255)/256, 256, 0, stream>>>(idx_i, idx_j, x, cursor, sij, diro);
  k_edge2<<<P_/128, 256, 0, stream>>>((const unsigned short*)hb, sij, diro,
                                      wb1, wb2, wb3,
                                      bein, beo1, beo2, Watt, batt,
                                      edgeb, e4o);
  k_agg<<<(N_+3)/4, 256, 0, stream>>>(offsets, edgeb, e4o, diro, wb4, Wvm,
                                      wsSem, wsN2, wsDv);
  k_mlp<<<(N_+127)/128, 256, 0, stream>>>(h, x, v, wsSem, wsN2, wsDv,
                                          wb5, wb6, wb7, wb8, wb9,
                                          bpn1, bpn2, bn1, bn2, bv1, Wv2,
                                          (float*)d_out);
}

// Round 11
// 333.622 us; speedup vs baseline: 1.3313x; 1.1304x over previous
//
#include <hip/hip_runtime.h>
#include <hip/hip_bf16.h>

#define DEV __device__ __forceinline__

constexpr int N_ = 25000;
constexpr int P_ = 400000;

// ---------------- ws layout (units of 4 bytes) ----------------
constexpr int align4(int xx){ return (xx+3)&~3; }
constexpr int OFF_CNT     = 0;                          // N ints
constexpr int OFF_OFFSETS = align4(OFF_CNT + N_);       // N+1 ints
constexpr int OFF_CURSOR  = align4(OFF_OFFSETS + N_ + 1);
constexpr int OFF_EDGE    = align4(OFF_CURSOR + N_);    // P*16 dwords (32 bf16 edge feats, sorted order)
constexpr int OFF_E4      = OFF_EDGE + P_*16;           // P*4  f32
constexpr int OFF_DIR     = OFF_E4 + P_*4;              // P*4  f32 (written by k_scatter2)
constexpr int OFF_SEM     = align4(OFF_DIR + P_*4);     // N*128 f32
constexpr int OFF_N2      = OFF_SEM + N_*128;           // N*32 f32
constexpr int OFF_DV      = OFF_N2 + N_*32;             // N*4 f32
constexpr int OFF_WB5     = OFF_DV + N_*4;              // 1024 dw (frag order)
constexpr int OFF_WB6     = OFF_WB5 + 1024;             // 2048 dw
constexpr int OFF_WB7     = OFF_WB6 + 2048;             // 8192 dw
constexpr int OFF_WB8     = OFF_WB7 + 8192;             // 2048 dw
constexpr int OFF_WB9     = OFF_WB8 + 2048;             // 2048 dw
constexpr int OFF_HB      = OFF_WB9 + 2048;             // h as bf16: N*32 dw
constexpr int OFF_SIJ     = OFF_HB + N_*32;             // sorted (i,j) pairs: P*2 ints
constexpr int OFF_WB1     = OFF_SIJ + P_*2;             // 8192 dw (frag order)
constexpr int OFF_WB2     = OFF_WB1 + 8192;             // 2048 dw
constexpr int OFF_WB3     = OFF_WB2 + 2048;             // 1024 dw
constexpr int OFF_WB4     = OFF_WB3 + 1024;             // 2048 dw (frag order + logical col permute)
constexpr int WS_UNITS    = OFF_WB4 + 2048;             // ~15.8M dw = 63 MB

// PhysNet RBF constants (K=50, r_max=0.5)
constexpr float MU0F  = 0.60653065971263342f;               // exp(-0.5)
constexpr float DMUF  = (1.0f - 0.60653065971263342f) / 49.0f;
constexpr float BETAF = 1.0f / ((0.04f * (1.0f - 0.60653065971263342f)) *
                                (0.04f * (1.0f - 0.60653065971263342f)));
constexpr float EPSF  = 1e-8f;

DEV float u2f(unsigned int u){ union{unsigned int i; float f;} c; c.i=u; return c.f; }
DEV unsigned int f2b16(float f){
  __hip_bfloat16 b = __float2bfloat16(f);
  unsigned short s; __builtin_memcpy(&s, &b, 2);
  return (unsigned int)s;
}
DEV unsigned int pack2(float a, float b){ return f2b16(a) | (f2b16(b) << 16); }
DEV float silu_f(float v){ return v / (1.0f + __expf(-v)); }

using short8 = __attribute__((ext_vector_type(8))) short;   // 8 bf16 (4 VGPRs)
using f32x4  = __attribute__((ext_vector_type(4))) float;
union U4S8 { uint4 u; short8 s; };
DEV short8 ld_frag(const void* p){ U4S8 c; c.u = *(const uint4*)p; return c.s; }
DEV f32x4 mfma16(short8 a, short8 b, f32x4 c){
  return __builtin_amdgcn_mfma_f32_16x16x32_bf16(a, b, c, 0, 0, 0);
}

// ---------------- prep0: histogram + h->bf16 + FRAGMENT-ORDERED weight transposes ----
// Fragment order: wbX[(nf*S + s)*64 + lane] = 8 bf16 of W^T[n=16nf+(lane&15)]
// [k = s*32 + (lane>>4)*8 .. +8]. A wave's B-frag load is then base + lane*16
// -> one coalesced 1 KB global_load_dwordx4 (was 64 scattered 16 B chunks).
__global__ void k_prep0(const int* __restrict__ idx_i,
                        const float* __restrict__ h,
                        const float* __restrict__ Wein, const float* __restrict__ Weo1,
                        const float* __restrict__ Weo2, const float* __restrict__ Wxm,
                        const float* __restrict__ Wpn1, const float* __restrict__ Wpn2,
                        const float* __restrict__ Wn1,  const float* __restrict__ Wn2,
                        const float* __restrict__ Wv1,
                        int* __restrict__ cnt, unsigned int* __restrict__ hb,
                        unsigned short* __restrict__ wb1, unsigned short* __restrict__ wb2,
                        unsigned short* __restrict__ wb3, unsigned short* __restrict__ wb4,
                        unsigned short* __restrict__ wb5, unsigned short* __restrict__ wb6,
                        unsigned short* __restrict__ wb7, unsigned short* __restrict__ wb8,
                        unsigned short* __restrict__ wb9){
  int t = blockIdx.x*256 + threadIdx.x;
  const int st = gridDim.x*256;
  if (t < P_) atomicAdd(&cnt[idx_i[t]], 1);
  for (int q=t; q<N_*32; q+=st){
    float2 a = *(const float2*)(h + (size_t)q*2);
    hb[q] = pack2(a.x, a.y);
  }
  // wb1: nf 0..7 (n=16nf+l15 over 0..127), s 0..3 (K=128)
  for (int q=t; q<8*4*64*8; q+=st){
    int e=q&7, lane=(q>>3)&63, sx=(q>>9)&3, nf=q>>11;
    int l15=lane&15, quad=lane>>4;
    int n = 16*nf + l15, k = sx*32 + quad*8 + e;
    float v = (n<50) ? Wein[k*50+n] : ((n<64) ? 0.f : Weo1[k*64+(n-64)]);
    wb1[q] = (unsigned short)f2b16(v);
  }
  // wb2: nf 0..3, s 0..1 (K=64); k<50 -> Weo1[128+k], k==50 -> Weo1[178], else 0
  for (int q=t; q<4*2*64*8; q+=st){
    int e=q&7, lane=(q>>3)&63, sx=(q>>9)&1, nf=q>>10;
    int l15=lane&15, quad=lane>>4;
    int n = 16*nf + l15, k = sx*32 + quad*8 + e;
    float v = (k<50) ? Weo1[(128+k)*64+n] : ((k==50) ? Weo1[178*64+n] : 0.f);
    wb2[q] = (unsigned short)f2b16(v);
  }
  // wb3: nf 0..1, s 0..1
  for (int q=t; q<2*2*64*8; q+=st){
    int e=q&7, lane=(q>>3)&63, sx=(q>>9)&1, nf=q>>10;
    int l15=lane&15, quad=lane>>4;
    int n = 16*nf + l15, k = sx*32 + quad*8 + e;
    wb3[q] = (unsigned short)f2b16(Weo2[k*32+n]);
  }
  // wb4: nf 0..7, K=32 (single s); physical n=16nf+l15 holds logical n_log=l15*8+nf
  for (int q=t; q<8*64*8; q+=st){
    int e=q&7, lane=(q>>3)&63, nf=q>>9;
    int l15=lane&15, quad=lane>>4;
    int k = quad*8 + e;
    int n_log = l15*8 + nf;
    int cc = n_log>>2, hh = n_log&3;
    wb4[q] = (unsigned short)f2b16(Wxm[(k*4+hh)*32 + cc]);
  }
  // wb5: nf 0..3, K=32
  for (int q=t; q<4*64*8; q+=st){
    int e=q&7, lane=(q>>3)&63, nf=q>>9;
    int l15=lane&15, quad=lane>>4;
    int n = 16*nf + l15, k = quad*8 + e;
    wb5[q] = (unsigned short)f2b16(Wpn1[k*64+n]);
  }
  // wb6 / wb8 / wb9: nf 0..3, s 0..1 (64x64 mats)
  for (int q=t; q<4*2*64*8; q+=st){
    int e=q&7, lane=(q>>3)&63, sx=(q>>9)&1, nf=q>>10;
    int l15=lane&15, quad=lane>>4;
    int n = 16*nf + l15, k = sx*32 + quad*8 + e;
    wb6[q] = (unsigned short)f2b16(Wpn2[k*64+n]);
    wb8[q] = (unsigned short)f2b16(Wn2[k*64+n]);
    wb9[q] = (unsigned short)f2b16(Wv1[k*64+n]);
  }
  // wb7: nf 0..3, s 0..7 (K=256)
  for (int q=t; q<4*8*64*8; q+=st){
    int e=q&7, lane=(q>>3)&63, sx=(q>>9)&7, nf=q>>12;
    int l15=lane&15, quad=lane>>4;
    int n = 16*nf + l15, k = sx*32 + quad*8 + e;
    wb7[q] = (unsigned short)f2b16(Wn1[k*64+n]);
  }
}

// ---------------- scan (2-barrier) ----------------
__global__ __launch_bounds__(1024) void k_scan(const int* __restrict__ cnt,
                                               int* __restrict__ offsets,
                                               int* __restrict__ cursor){
  __shared__ int swv[16];
  const int t = threadIdx.x;
  const int wv = t >> 6, ln = t & 63;
  constexpr int CH = (N_ + 1023)/1024;   // 25
  int b = t*CH, e = b+CH;
  if (b > N_) b = N_;
  if (e > N_) e = N_;
  int s = 0;
  for (int q=b; q<e; q++) s += cnt[q];
  int incl = s;
  #pragma unroll
  for (int off=1; off<64; off<<=1){
    int vv = __shfl_up(incl, off);
    if (ln >= off) incl += vv;
  }
  if (ln == 63) swv[wv] = incl;
  __syncthreads();
  if (wv == 0 && ln < 16){
    int w = swv[ln];
    #pragma unroll
    for (int off=1; off<16; off<<=1){
      int vv = __shfl_up(w, off);
      if (ln >= off) w += vv;
    }
    swv[ln] = w;
  }
  __syncthreads();
  const int wpre = (wv > 0) ? swv[wv-1] : 0;
  int run = wpre + incl - s;
  for (int q=b; q<e; q++){ offsets[q] = run; cursor[q] = run; run += cnt[q]; }
  if (t == 1023) offsets[N_] = run;
}

// ---------------- scatter + fused geometry ----------------
__global__ void k_scatter2(const int* __restrict__ idx_i, const int* __restrict__ idx_j,
                           const float* __restrict__ x,
                           int* __restrict__ cursor,
                           int* __restrict__ sij, float* __restrict__ dir4){
  int t = blockIdx.x*256 + threadIdx.x;
  if (t >= P_) return;
  int i = idx_i[t], j = idx_j[t];
  int pos = atomicAdd(&cursor[i], 1);
  *(int2*)(sij + (size_t)pos*2) = make_int2(i, j);
  float xi0=x[i*3], xi1=x[i*3+1], xi2=x[i*3+2];
  float xj0=x[j*3], xj1=x[j*3+1], xj2=x[j*3+2];
  float rx=xj0-xi0, ry=xj1-xi1, rz=xj2-xi2;
  float d = sqrtf(rx*rx+ry*ry+rz*rz+EPSF);
  float iv = 1.0f/(d+EPSF);
  *(float4*)(dir4 + (size_t)pos*4) = make_float4(rx*iv, ry*iv, rz*iv, d);
}

// ---------------- MFMA edge kernel: frag-ordered B loads, low-AGPR split ----------------
__global__ __launch_bounds__(256, 4) void k_edge2(
    const unsigned short* __restrict__ hb,
    const int* __restrict__ sij, const float* __restrict__ dir4,
    const unsigned short* __restrict__ wb1, const unsigned short* __restrict__ wb2,
    const unsigned short* __restrict__ wb3,
    const float* __restrict__ bein, const float* __restrict__ beo1,
    const float* __restrict__ beo2, const float* __restrict__ Watt,
    const float* __restrict__ batt,
    unsigned int* __restrict__ edge_out, float* __restrict__ e4_out)
{
  __shared__ __align__(16) unsigned char sAll[4*9216];   // 36864 B
  __shared__ float sdv[128];
  __shared__ float semd[128];

  const int tid  = threadIdx.x;
  const int wv   = tid >> 6;
  const int lane = tid & 63;
  const int l15  = lane & 15;
  const int quad = lane >> 4;
  const int pbase = blockIdx.x * 128;
  unsigned char* sW = sAll + wv*9216;

  // ---- geometry: contiguous dir4 read (lanes 0..31) ----
  if (lane < 32){
    int row = 32*wv + lane;
    float4 dv = *(const float4*)(dir4 + (size_t)(pbase + row)*4);
    sdv[row] = dv.w;
    semd[row] = __expf(-dv.w);
  }

  // ---- stage A1 = hcat bf16 (2 threads/row; one int2 load then 128 B copy) ----
  {
    int rr = lane >> 1;
    int2 ij = *(const int2*)(sij + (size_t)(pbase + 32*wv + rr)*2);
    int hidx = (lane & 1) ? ij.y : ij.x;
    const uint4* hp = (const uint4*)(hb + (size_t)hidx*64);
    unsigned char* dst = sW + rr*264 + (lane&1)*128;
    #pragma unroll
    for (int q=0;q<8;q++) *(uint4*)(dst + q*16) = hp[q];
  }

  // ---- load all A-fragments into registers ----
  short8 af0[4], af1[4];
  #pragma unroll
  for (int s=0; s<4; s++){
    int koff = s*32 + quad*8;
    af0[s] = ld_frag(sW + l15*264      + koff*2);
    af1[s] = ld_frag(sW + (16+l15)*264 + koff*2);
  }

  // ---- GEMM-1a: [32 x 128] @ WB1[nf 0..3] (Wein) — coalesced frag loads ----
  f32x4 acc[2][4];
  #pragma unroll
  for (int mf=0; mf<2; mf++)
    #pragma unroll
    for (int nf=0; nf<4; nf++){
      int nn = 16*nf + l15;
      float bias = (nn < 50) ? bein[nn] : 0.f;
      acc[mf][nf] = (f32x4){bias, bias, bias, bias};
    }
  #pragma unroll
  for (int s=0; s<4; s++){
    #pragma unroll
    for (int nf=0; nf<4; nf++){
      short8 b = ld_frag((const unsigned char*)wb1 + (size_t)((nf*4 + s)*64 + lane)*16);
      acc[0][nf] = mfma16(af0[s], b, acc[0][nf]);
      acc[1][nf] = mfma16(af1[s], b, acc[1][nf]);
    }
  }

  // ---- epilogue 1: RBF -> A2 bf16 [lrow][72 ushort] at sW+0 ----
  #pragma unroll
  for (int mf=0; mf<2; mf++)
    #pragma unroll
    for (int nf=0; nf<4; nf++){
      int n = 16*nf + l15;
      float mu = MU0F + (float)n*DMUF;
      #pragma unroll
      for (int reg=0; reg<4; reg++){
        int lrow = 16*mf + quad*4 + reg;
        int grow = 32*wv + lrow;
        float t = semd[grow] - mu;
        float fv = acc[mf][nf][reg] * __expf(-BETAF*t*t);
        unsigned short ob;
        if (n < 50)       ob = (unsigned short)f2b16(fv);
        else if (n == 50) ob = (unsigned short)f2b16(sdv[grow]);
        else              ob = 0;
        ((unsigned short*)sW)[lrow*72 + n] = ob;
      }
    }

  // ---- GEMM-1b: @ WB1[nf 4..7] (Weo1-top) into reused acc ----
  #pragma unroll
  for (int mf=0; mf<2; mf++)
    #pragma unroll
    for (int nf=0; nf<4; nf++){
      float bias = beo1[16*nf + l15];
      acc[mf][nf] = (f32x4){bias, bias, bias, bias};
    }
  #pragma unroll
  for (int s=0; s<4; s++){
    #pragma unroll
    for (int nf=0; nf<4; nf++){
      short8 b = ld_frag((const unsigned char*)wb1 + (size_t)(((4+nf)*4 + s)*64 + lane)*16);
      acc[0][nf] = mfma16(af0[s], b, acc[0][nf]);
      acc[1][nf] = mfma16(af1[s], b, acc[1][nf]);
    }
  }

  // ---- GEMM-2: += A2 [32 x 64] @ WB2 [64 x 64] ----
  #pragma unroll
  for (int s=0; s<2; s++){
    int koff = s*32 + quad*8;
    short8 a0 = ld_frag(sW + l15*144      + koff*2);
    short8 a1 = ld_frag(sW + (16+l15)*144 + koff*2);
    #pragma unroll
    for (int nf=0; nf<4; nf++){
      short8 b = ld_frag((const unsigned char*)wb2 + (size_t)((nf*2 + s)*64 + lane)*16);
      acc[0][nf] = mfma16(a0, b, acc[0][nf]);
      acc[1][nf] = mfma16(a1, b, acc[1][nf]);
    }
  }

  // ---- epilogue 2: silu -> A3 bf16 at sW+4608 ----
  unsigned char* A3 = sW + 4608;
  #pragma unroll
  for (int mf=0; mf<2; mf++)
    #pragma unroll
    for (int nf=0; nf<4; nf++){
      int n = 16*nf + l15;
      #pragma unroll
      for (int reg=0; reg<4; reg++){
        int lrow = 16*mf + quad*4 + reg;
        ((unsigned short*)A3)[lrow*72 + n] = (unsigned short)f2b16(silu_f(acc[mf][nf][reg]));
      }
    }

  // ---- GEMM-3: [32 x 64] @ WB3 [64 x 32] ----
  f32x4 acc3[2][2];
  #pragma unroll
  for (int mf=0; mf<2; mf++)
    #pragma unroll
    for (int nf=0; nf<2; nf++){
      float bias = beo2[16*nf + l15];
      acc3[mf][nf] = (f32x4){bias, bias, bias, bias};
    }
  #pragma unroll
  for (int s=0; s<2; s++){
    int koff = s*32 + quad*8;
    short8 a0 = ld_frag(A3 + l15*144      + koff*2);
    short8 a1 = ld_frag(A3 + (16+l15)*144 + koff*2);
    #pragma unroll
    for (int nf=0; nf<2; nf++){
      short8 b = ld_frag((const unsigned char*)wb3 + (size_t)((nf*2 + s)*64 + lane)*16);
      acc3[0][nf] = mfma16(a0, b, acc3[0][nf]);
      acc3[1][nf] = mfma16(a1, b, acc3[1][nf]);
    }
  }

  // ---- epilogue 3: C3 f32 [lrow][36 f32] at sW+0 ----
  #pragma unroll
  for (int mf=0; mf<2; mf++)
    #pragma unroll
    for (int nf=0; nf<2; nf++){
      int n = 16*nf + l15;
      #pragma unroll
      for (int reg=0; reg<4; reg++){
        int lrow = 16*mf + quad*4 + reg;
        ((float*)sW)[lrow*36 + n] = acc3[mf][nf][reg];
      }
    }

  // ---- attention + stores (2 lanes per row) ----
  {
    int rr = lane >> 1;
    int p = pbase + 32*wv + rr;
    int cb = (lane & 1) * 16;
    const float* er = (const float*)(sW + rr*144);
    float l0, l1, l2, l3;
    if ((lane & 1) == 0){ l0 = batt[0]; l1 = batt[1]; l2 = batt[2]; l3 = batt[3]; }
    else                { l0 = l1 = l2 = l3 = 0.f; }
    float ecache[16];
    #pragma unroll
    for (int c=0;c<16;c++){
      float ev = er[cb + c];
      ecache[c] = ev;
      const float4 wr = *(const float4*)(Watt + (cb + c)*4);
      l0 += ev*wr.x; l1 += ev*wr.y; l2 += ev*wr.z; l3 += ev*wr.w;
    }
    l0 += __shfl_xor(l0,1); l1 += __shfl_xor(l1,1);
    l2 += __shfl_xor(l2,1); l3 += __shfl_xor(l3,1);
    if ((lane & 1) == 0){
      float e0 = __expf(l0 > 0.f ? l0 : 2.f*(__expf(l0*0.5f)-1.f));
      float e1 = __expf(l1 > 0.f ? l1 : 2.f*(__expf(l1*0.5f)-1.f));
      float e2 = __expf(l2 > 0.f ? l2 : 2.f*(__expf(l2*0.5f)-1.f));
      float e3 = __expf(l3 > 0.f ? l3 : 2.f*(__expf(l3*0.5f)-1.f));
      *(float4*)(e4_out + (size_t)p*4) = make_float4(e0, e1, e2, e3);
    }
    uint4 o1 = make_uint4(pack2(ecache[0],ecache[1]),  pack2(ecache[2],ecache[3]),
                          pack2(ecache[4],ecache[5]),  pack2(ecache[6],ecache[7]));
    uint4 o2 = make_uint4(pack2(ecache[8],ecache[9]),  pack2(ecache[10],ecache[11]),
                          pack2(ecache[12],ecache[13]),pack2(ecache[14],ecache[15]));
    unsigned int* ep = edge_out + (size_t)p*16 + (lane&1)*8;
    *(uint4*)(ep)     = o1;
    *(uint4*)(ep + 4) = o2;
  }
}

// ---------------- aggregation: 1 node/wave, frag-ordered b4, b128 writeback ----------
__global__ __launch_bounds__(256, 4) void k_agg(
    const int* __restrict__ offsets,
    const unsigned int* __restrict__ edgeb,
    const float* __restrict__ e4,
    const float* __restrict__ dir4,
    const unsigned short* __restrict__ wb4,
    const float* __restrict__ Wvm,
    float* __restrict__ wsSem, float* __restrict__ wsN2, float* __restrict__ wsDv)
{
  __shared__ __align__(16) unsigned char sAllB[4*10240];
  const int wv   = threadIdx.x >> 6;
  const int lane = threadIdx.x & 63;
  unsigned char* sA = sAllB + wv*10240;
  unsigned char* gC = sA + 2048;

  const int c    = lane & 31;
  const int l15  = lane & 15;
  const int quad = lane >> 4;
  const int half = lane >> 5;
  const bool low = (lane < 32);

  short8 b4[8];
  #pragma unroll
  for (int nf=0; nf<8; nf++)
    b4[nf] = ld_frag((const unsigned char*)wb4 + (size_t)(nf*64 + lane)*16);
  const float wvm_c = Wvm[c];

  const int i = blockIdx.x*4 + wv;
  if (i >= N_) return;
  const int n0 = offsets[i], n1 = offsets[i+1];
  const int cnt = n1 - n0;

  // first-chunk staging before the denominator pass (independent streams)
  {
    const int nc0 = min(32, cnt);
    if (lane*32 < nc0*64){
      const uint4* src = (const uint4*)(edgeb + (size_t)n0*16 + lane*8);
      *(uint4*)(sA + lane*32)      = src[0];
      *(uint4*)(sA + lane*32 + 16) = src[1];
    }
  }

  float d0=0.f,d1=0.f,d2=0.f,d3=0.f;
  for (int s = n0 + lane; s < n1; s += 64){
    const float4 ev = *(const float4*)(e4 + (size_t)s*4);
    d0+=ev.x; d1+=ev.y; d2+=ev.z; d3+=ev.w;
  }
  #pragma unroll
  for (int off=32; off>=1; off>>=1){
    d0 += __shfl_xor(d0,off); d1 += __shfl_xor(d1,off);
    d2 += __shfl_xor(d2,off); d3 += __shfl_xor(d3,off);
  }
  const float i0 = (cnt>0)?1.f/d0:0.f, i1 = (cnt>0)?1.f/d1:0.f;
  const float i2 = (cnt>0)?1.f/d2:0.f, i3 = (cnt>0)?1.f/d3:0.f;

  float sem4[4] = {0.f,0.f,0.f,0.f};
  float cx=0.f,cy=0.f,cz=0.f, gx=0.f,gy=0.f,gz=0.f;

  bool staged = true;                    // first chunk already staged
  for (int base = n0; base < n1; base += 32){
    const int nc = min(32, n1 - base);
    if (!staged){
      if (lane*32 < nc*64){
        const uint4* src = (const uint4*)(edgeb + (size_t)base*16 + lane*8);
        *(uint4*)(sA + lane*32)      = src[0];
        *(uint4*)(sA + lane*32 + 16) = src[1];
      }
    }
    staged = false;
    // half 0: rows 0..15 — compute then b128 writeback (logical n = l15*8 + nf)
    {
      short8 a0 = ld_frag(sA + l15*64 + quad*16);
      f32x4 accg[8];
      #pragma unroll
      for (int nf=0; nf<8; nf++){
        f32x4 z = (f32x4){0.f,0.f,0.f,0.f};
        accg[nf] = mfma16(a0, b4[nf], z);
      }
      #pragma unroll
      for (int reg=0; reg<4; reg++){
        int row = quad*4 + reg;
        uint4 o = make_uint4(pack2(accg[0][reg],accg[1][reg]),
                             pack2(accg[2][reg],accg[3][reg]),
                             pack2(accg[4][reg],accg[5][reg]),
                             pack2(accg[6][reg],accg[7][reg]));
        *(uint4*)(gC + row*256 + l15*16) = o;
      }
    }
    // half 1: rows 16..31
    if (nc > 16){
      short8 a1 = ld_frag(sA + (16+l15)*64 + quad*16);
      f32x4 accg[8];
      #pragma unroll
      for (int nf=0; nf<8; nf++){
        f32x4 z = (f32x4){0.f,0.f,0.f,0.f};
        accg[nf] = mfma16(a1, b4[nf], z);
      }
      #pragma unroll
      for (int reg=0; reg<4; reg++){
        int row = 16 + quad*4 + reg;
        uint4 o = make_uint4(pack2(accg[0][reg],accg[1][reg]),
                             pack2(accg[2][reg],accg[3][reg]),
                             pack2(accg[4][reg],accg[5][reg]),
                             pack2(accg[6][reg],accg[7][reg]));
        *(uint4*)(gC + row*256 + l15*16) = o;
      }
    }
    // inner: 2 pairs/iter, next iteration's e4/dir4 prefetched into regs
    float4 evc, dvc;
    {
      int s0 = base + min(half, nc-1);
      evc = *(const float4*)(e4 + (size_t)s0*4);
      dvc = *(const float4*)(dir4 + (size_t)s0*4);
    }
    for (int t0 = 0; t0 < nc; t0 += 2){
      const float4 ev = evc, dv = dvc;
      const int nt = t0 + 2 + half;
      if (nt < nc){
        int s2 = base + nt;
        evc = *(const float4*)(e4 + (size_t)s2*4);
        dvc = *(const float4*)(dir4 + (size_t)s2*4);
      }
      const int rloc = t0 + half;
      const bool act = rloc < nc;
      const float aw0 = ev.x*i0, aw1 = ev.y*i1, aw2 = ev.z*i2, aw3 = ev.w*i3;
      uint2 gv = *(const uint2*)(gC + rloc*256 + c*8);
      float g0=u2f(gv.x<<16), g1=u2f(gv.x&0xffff0000u);
      float g2=u2f(gv.y<<16), g3=u2f(gv.y&0xffff0000u);
      float tp = aw0*g0 + aw1*g1 + aw2*g2 + aw3*g3;
      float tt = fminf(fmaxf(tp, -15.f), 15.f);
      float ex = __expf(2.f*tt);
      float th = (ex-1.f)/(ex+1.f);
      unsigned int ew = *(const unsigned int*)(sA + rloc*64 + (c>>1)*4);
      float ec = (c & 1) ? u2f(ew & 0xffff0000u) : u2f(ew << 16);
      if (act){
        sem4[0] += ec*aw0; sem4[1] += ec*aw1;
        sem4[2] += ec*aw2; sem4[3] += ec*aw3;
        cx += th*dv.x; cy += th*dv.y; cz += th*dv.z;
        float tw = th*wvm_c;
        gx += tw*dv.x; gy += tw*dv.y; gz += tw*dv.z;
      }
    }
  }

  #pragma unroll
  for (int j=0;j<4;j++) sem4[j] += __shfl_xor(sem4[j], 32);
  cx += __shfl_xor(cx,32); cy += __shfl_xor(cy,32); cz += __shfl_xor(cz,32);
  #pragma unroll
  for (int off=32; off>=1; off>>=1){
    gx += __shfl_xor(gx,off); gy += __shfl_xor(gy,off); gz += __shfl_xor(gz,off);
  }
  const float invc = 1.f/(float)(cnt > 1 ? cnt : 1);
  if (low){
    float mx = cx*invc, my = cy*invc, mz = cz*invc;
    wsN2[(size_t)i*32 + c] = mx*mx + my*my + mz*mz;
    *(float4*)(wsSem + (size_t)i*128 + 4*c) = make_float4(sem4[0], sem4[1], sem4[2], sem4[3]);
  }
  if (lane == 0)
    *(float4*)(wsDv + (size_t)i*4) = make_float4(gx*invc, gy*invc, gz*invc, 0.f);
}

// ---------------- node MLP kernel: batched MFMA GEMM, frag-ordered weights ----------
__global__ __launch_bounds__(256) void k_mlp(
    const float* __restrict__ h, const float* __restrict__ x, const float* __restrict__ v,
    const float* __restrict__ wsSem, const float* __restrict__ wsN2,
    const float* __restrict__ wsDv,
    const unsigned short* __restrict__ wb5, const unsigned short* __restrict__ wb6,
    const unsigned short* __restrict__ wb7, const unsigned short* __restrict__ wb8,
    const unsigned short* __restrict__ wb9,
    const float* __restrict__ bpn1, const float* __restrict__ bpn2,
    const float* __restrict__ bn1,  const float* __restrict__ bn2,
    const float* __restrict__ bv1,  const float* __restrict__ Wv2,
    float* __restrict__ out)
{
  __shared__ __align__(16) unsigned char sH[128*136];
  __shared__ __align__(16) unsigned char sSem[128*264];
  __shared__ __align__(16) unsigned char sSp[128*136];
  __shared__ __align__(16) unsigned char sN2[128*72];
  __shared__ __align__(16) unsigned char sTmp[128*136];

  const int tid  = threadIdx.x;
  const int wv   = tid >> 6;
  const int lane = tid & 63;
  const int l15  = lane & 15;
  const int quad = lane >> 4;
  const int i0   = blockIdx.x*128;
  const int r0   = 32*wv;

  for (int idx = tid; idx < 128*16; idx += 256){
    int row = idx >> 4, c4 = idx & 15;
    int node = min(i0 + row, N_-1);
    float4 a = *(const float4*)(h + (size_t)node*64 + c4*4);
    *(uint2*)(sH + row*136 + c4*8) = make_uint2(pack2(a.x,a.y), pack2(a.z,a.w));
  }
  for (int idx = tid; idx < 128*32; idx += 256){
    int row = idx >> 5, c4 = idx & 31;
    int node = min(i0 + row, N_-1);
    float4 a = *(const float4*)(wsSem + (size_t)node*128 + c4*4);
    *(uint2*)(sSem + row*264 + c4*8) = make_uint2(pack2(a.x,a.y), pack2(a.z,a.w));
  }
  for (int idx = tid; idx < 128*8; idx += 256){
    int row = idx >> 3, c4 = idx & 7;
    int node = min(i0 + row, N_-1);
    float4 a = *(const float4*)(wsN2 + (size_t)node*32 + c4*4);
    *(uint2*)(sN2 + row*72 + c4*8) = make_uint2(pack2(a.x,a.y), pack2(a.z,a.w));
  }
  __syncthreads();

  // S1
  {
    f32x4 acc[2][4];
    #pragma unroll
    for (int mf=0; mf<2; mf++)
      #pragma unroll
      for (int nf=0; nf<4; nf++){ float b = bpn1[16*nf+l15]; acc[mf][nf] = (f32x4){b,b,b,b}; }
    short8 a0 = ld_frag(sN2 + (r0+l15)*72 + quad*16);
    short8 a1 = ld_frag(sN2 + (r0+16+l15)*72 + quad*16);
    #pragma unroll
    for (int nf=0; nf<4; nf++){
      short8 b = ld_frag((const unsigned char*)wb5 + (size_t)(nf*64 + lane)*16);
      acc[0][nf] = mfma16(a0, b, acc[0][nf]);
      acc[1][nf] = mfma16(a1, b, acc[1][nf]);
    }
    #pragma unroll
    for (int mf=0; mf<2; mf++)
      #pragma unroll
      for (int nf=0; nf<4; nf++){
        int n = 16*nf + l15;
        #pragma unroll
        for (int reg=0; reg<4; reg++){
          int row = r0 + 16*mf + quad*4 + reg;
          ((unsigned short*)(sTmp + row*136))[n] = (unsigned short)f2b16(silu_f(acc[mf][nf][reg]));
        }
      }
  }
  // S2
  {
    f32x4 acc[2][4];
    #pragma unroll
    for (int mf=0; mf<2; mf++)
      #pragma unroll
      for (int nf=0; nf<4; nf++){ float b = bpn2[16*nf+l15]; acc[mf][nf] = (f32x4){b,b,b,b}; }
    #pragma unroll
    for (int s=0; s<2; s++){
      int koff = s*32 + quad*8;
      short8 a0 = ld_frag(sTmp + (r0+l15)*136 + koff*2);
      short8 a1 = ld_frag(sTmp + (r0+16+l15)*136 + koff*2);
      #pragma unroll
      for (int nf=0; nf<4; nf++){
        short8 b = ld_frag((const unsigned char*)wb6 + (size_t)((nf*2 + s)*64 + lane)*16);
        acc[0][nf] = mfma16(a0, b, acc[0][nf]);
        acc[1][nf] = mfma16(a1, b, acc[1][nf]);
      }
    }
    #pragma unroll
    for (int mf=0; mf<2; mf++)
      #pragma unroll
      for (int nf=0; nf<4; nf++){
        int n = 16*nf + l15;
        #pragma unroll
        for (int reg=0; reg<4; reg++){
          int row = r0 + 16*mf + quad*4 + reg;
          ((unsigned short*)(sSp + row*136))[n] = (unsigned short)f2b16(silu_f(acc[mf][nf][reg]));
        }
      }
  }
  // N1 (K=256)
  {
    f32x4 acc[2][4];
    #pragma unroll
    for (int mf=0; mf<2; mf++)
      #pragma unroll
      for (int nf=0; nf<4; nf++){ float b = bn1[16*nf+l15]; acc[mf][nf] = (f32x4){b,b,b,b}; }
    #pragma unroll
    for (int s=0; s<8; s++){
      int koff = s*32 + quad*8;
      const unsigned char *pa0, *pa1;
      if (koff < 64){ pa0 = sH + (r0+l15)*136 + koff*2;          pa1 = sH + (r0+16+l15)*136 + koff*2; }
      else if (koff < 192){ pa0 = sSem + (r0+l15)*264 + (koff-64)*2;  pa1 = sSem + (r0+16+l15)*264 + (koff-64)*2; }
      else { pa0 = sSp + (r0+l15)*136 + (koff-192)*2;            pa1 = sSp + (r0+16+l15)*136 + (koff-192)*2; }
      short8 a0 = ld_frag(pa0);
      short8 a1 = ld_frag(pa1);
      #pragma unroll
      for (int nf=0; nf<4; nf++){
        short8 b = ld_frag((const unsigned char*)wb7 + (size_t)((nf*8 + s)*64 + lane)*16);
        acc[0][nf] = mfma16(a0, b, acc[0][nf]);
        acc[1][nf] = mfma16(a1, b, acc[1][nf]);
      }
    }
    #pragma unroll
    for (int mf=0; mf<2; mf++)
      #pragma unroll
      for (int nf=0; nf<4; nf++){
        int n = 16*nf + l15;
        #pragma unroll
        for (int reg=0; reg<4; reg++){
          int row = r0 + 16*mf + quad*4 + reg;
          ((unsigned short*)(sTmp + row*136))[n] = (unsigned short)f2b16(silu_f(acc[mf][nf][reg]));
        }
      }
  }
  // N2 + residual
  {
    f32x4 acc[2][4];
    #pragma unroll
    for (int mf=0; mf<2; mf++)
      #pragma unroll
      for (int nf=0; nf<4; nf++){ float b = bn2[16*nf+l15]; acc[mf][nf] = (f32x4){b,b,b,b}; }
    #pragma unroll
    for (int s=0; s<2; s++){
      int koff = s*32 + quad*8;
      short8 a0 = ld_frag(sTmp + (r0+l15)*136 + koff*2);
      short8 a1 = ld_frag(sTmp + (r0+16+l15)*136 + koff*2);
      #pragma unroll
      for (int nf=0; nf<4; nf++){
        short8 b = ld_frag((const unsigned char*)wb8 + (size_t)((nf*2 + s)*64 + lane)*16);
        acc[0][nf] = mfma16(a0, b, acc[0][nf]);
        acc[1][nf] = mfma16(a1, b, acc[1][nf]);
      }
    }
    #pragma unroll
    for (int mf=0; mf<2; mf++)
      #pragma unroll
      for (int nf=0; nf<4; nf++){
        int n = 16*nf + l15;
        #pragma unroll
        for (int reg=0; reg<4; reg++){
          int row = r0 + 16*mf + quad*4 + reg;
          int node = i0 + row;
          float hv = (node < N_) ? h[(size_t)node*64 + n] : 0.f;
          float hnew = hv + silu_f(acc[mf][nf][reg]);
          if (node < N_) out[(size_t)node*64 + n] = hnew;
          ((unsigned short*)(sH + row*136))[n] = (unsigned short)f2b16(hnew);
        }
      }
  }
  // V1 + gate + v/x
  {
    f32x4 acc[2][4];
    #pragma unroll
    for (int mf=0; mf<2; mf++)
      #pragma unroll
      for (int nf=0; nf<4; nf++){ float b = bv1[16*nf+l15]; acc[mf][nf] = (f32x4){b,b,b,b}; }
    #pragma unroll
    for (int s=0; s<2; s++){
      int koff = s*32 + quad*8;
      short8 a0 = ld_frag(sH + (r0+l15)*136 + koff*2);
      short8 a1 = ld_frag(sH + (r0+16+l15)*136 + koff*2);
      #pragma unroll
      for (int nf=0; nf<4; nf++){
        short8 b = ld_frag((const unsigned char*)wb9 + (size_t)((nf*2 + s)*64 + lane)*16);
        acc[0][nf] = mfma16(a0, b, acc[0][nf]);
        acc[1][nf] = mfma16(a1, b, acc[1][nf]);
      }
    }
    float part[2][4] = {{0.f,0.f,0.f,0.f},{0.f,0.f,0.f,0.f}};
    #pragma unroll
    for (int mf=0; mf<2; mf++)
      #pragma unroll
      for (int nf=0; nf<4; nf++){
        float w2 = Wv2[16*nf + l15];
        #pragma unroll
        for (int reg=0; reg<4; reg++)
          part[mf][reg] += silu_f(acc[mf][nf][reg]) * w2;
      }
    #pragma unroll
    for (int mf=0; mf<2; mf++)
      #pragma unroll
      for (int reg=0; reg<4; reg++){
        #pragma unroll
        for (int off=1; off<16; off<<=1)
          part[mf][reg] += __shfl_xor(part[mf][reg], off);
      }
    if (l15 == 0){
      #pragma unroll
      for (int mf=0; mf<2; mf++)
        #pragma unroll
        for (int reg=0; reg<4; reg++){
          int row = r0 + 16*mf + quad*4 + reg;
          int node = i0 + row;
          if (node < N_){
            float gate = 2.f/(1.f + __expf(-part[mf][reg]));
            float4 dvv = *(const float4*)(wsDv + (size_t)node*4);
            float dvs[3] = {dvv.x, dvv.y, dvv.z};
            #pragma unroll
            for (int ax=0; ax<3; ax++){
              float vn = gate * v[(size_t)node*3 + ax] + dvs[ax];
              out[(size_t)N_*64 + (size_t)node*3 + ax]                 = x[(size_t)node*3 + ax] + vn;
              out[(size_t)N_*64 + (size_t)N_*3 + (size_t)node*3 + ax]  = vn;
            }
          }
        }
    }
  }
}

// ---------------- launch ----------------
extern "C" void kernel_launch(void* const* d_in, const int* in_sizes, int n_in,
                              void* d_out, int out_size, void* d_ws, size_t ws_size,
                              hipStream_t stream)
{
  const float* h = (const float*)d_in[0];
  const float* x = (const float*)d_in[1];
  const float* v = (const float*)d_in[2];
  const int* idx_i = (const int*)d_in[3];
  const int* idx_j = (const int*)d_in[4];
  const float* Wein = (const float*)d_in[5];  const float* bein = (const float*)d_in[6];
  const float* Weo1 = (const float*)d_in[7];  const float* beo1 = (const float*)d_in[8];
  const float* Weo2 = (const float*)d_in[9];  const float* beo2 = (const float*)d_in[10];
  const float* Watt = (const float*)d_in[11]; const float* batt = (const float*)d_in[12];
  const float* Wxm  = (const float*)d_in[13]; const float* Wvm  = (const float*)d_in[14];
  const float* Wpn1 = (const float*)d_in[15]; const float* bpn1 = (const float*)d_in[16];
  const float* Wpn2 = (const float*)d_in[17]; const float* bpn2 = (const float*)d_in[18];
  const float* Wn1  = (const float*)d_in[19]; const float* bn1  = (const float*)d_in[20];
  const float* Wn2  = (const float*)d_in[21]; const float* bn2  = (const float*)d_in[22];
  const float* Wv1  = (const float*)d_in[23]; const float* bv1  = (const float*)d_in[24];
  const float* Wv2  = (const float*)d_in[25];

  float* wsf        = (float*)d_ws;
  int*   cnt        = (int*)(wsf + OFF_CNT);
  int*   offsets    = (int*)(wsf + OFF_OFFSETS);
  int*   cursor     = (int*)(wsf + OFF_CURSOR);
  unsigned int* edgeb = (unsigned int*)(wsf + OFF_EDGE);
  float* e4o        = wsf + OFF_E4;
  float* diro       = wsf + OFF_DIR;
  float* wsSem      = wsf + OFF_SEM;
  float* wsN2       = wsf + OFF_N2;
  float* wsDv       = wsf + OFF_DV;
  unsigned short* wb1 = (unsigned short*)(wsf + OFF_WB1);
  unsigned short* wb2 = (unsigned short*)(wsf + OFF_WB2);
  unsigned short* wb3 = (unsigned short*)(wsf + OFF_WB3);
  unsigned short* wb4 = (unsigned short*)(wsf + OFF_WB4);
  unsigned short* wb5 = (unsigned short*)(wsf + OFF_WB5);
  unsigned short* wb6 = (unsigned short*)(wsf + OFF_WB6);
  unsigned short* wb7 = (unsigned short*)(wsf + OFF_WB7);
  unsigned short* wb8 = (unsigned short*)(wsf + OFF_WB8);
  unsigned short* wb9 = (unsigned short*)(wsf + OFF_WB9);
  unsigned int*   hb  = (unsigned int*)(wsf + OFF_HB);
  int*            sij = (int*)(wsf + OFF_SIJ);

  hipMemsetAsync(cnt, 0, N_*sizeof(int), stream);
  k_prep0<<<(P_+255)/256, 256, 0, stream>>>(idx_i, h, Wein, Weo1, Weo2, Wxm,
                                            Wpn1, Wpn2, Wn1, Wn2, Wv1,
                                            cnt, hb, wb1, wb2, wb3, wb4,
                                            wb5, wb6, wb7, wb8, wb9);
  k_scan<<<1, 1024, 0, stream>>>(cnt, offsets, cursor);
  k_scatter2<<<(P_+255)/256, 256, 0, stream>>>(idx_i, idx_j, x, cursor, sij, diro);
  k_edge2<<<P_/128, 256, 0, stream>>>((const unsigned short*)hb, sij, diro,
                                      wb1, wb2, wb3,
                                      bein, beo1, beo2, Watt, batt,
                                      edgeb, e4o);
  k_agg<<<(N_+3)/4, 256, 0, stream>>>(offsets, edgeb, e4o, diro, wb4, Wvm,
                                      wsSem, wsN2, wsDv);
  k_mlp<<<(N_+127)/128, 256, 0, stream>>>(h, x, v, wsSem, wsN2, wsDv,
                                          wb5, wb6, wb7, wb8, wb9,
                                          bpn1, bpn2, bn1, bn2, bv1, Wv2,
                                          (float*)d_out);
}